// Round 2
// baseline (174.703 us; speedup 1.0000x reference)
//
#include <hip/hip_runtime.h>
#include <hip/hip_bf16.h>

typedef __bf16 bf16x8 __attribute__((ext_vector_type(8)));
typedef __bf16 bf16x4 __attribute__((ext_vector_type(4)));
typedef float  f32x4  __attribute__((ext_vector_type(4)));

#define B_  8
#define T_  2048
#define D_  1024
#define HS_ 64

// ---------------------------------------------------------------------------
// fp32 inputs/outputs; bf16 MFMA internally.
// pack_w -> qkv_fused (M=16/wave, K-split waves, BATCHED Wp loads)
//        -> attn_partial (S^T scheme, BARRIER-FREE: frag-direct L2 loads)
//        -> attn_merge (two-pass, dependency-free loads, 2 blocks/CU).
//
// Round-10/11 theory: all kernels < fill time (41us) but total 148us vs
// ~35us structural floor => latency/sync bound, not roofline.
//  - attn_partial: LDS staging only re-permuted data; the permutation is now
//    folded into per-lane global addresses (K/V tiles are L2-resident).
//    Zero LDS, zero __syncthreads; waves free-run, loads pipeline.
//  - attn_merge: serial m/alpha expf chain between Opart loads removed via
//    two-pass (scales from Ml first, then 16 independent f32x4 loads).
// ---------------------------------------------------------------------------

// Kernel 0: pack the three [D,HS] fp32 weights into bf16 MFMA-fragment order.
__global__ __launch_bounds__(256) void pack_w(
    const float* __restrict__ Wq, const float* __restrict__ Wk,
    const float* __restrict__ Wv, __bf16* __restrict__ Wp)
{
    const int t    = blockIdx.x * 256 + threadIdx.x;   // 0..24575
    const int lane = t & 63;
    const int pg   = t >> 6;                           // 0..383
    const int s    = pg & 3;
    const int c    = (pg >> 2) & 31;
    const int p    = pg >> 7;
    const int m16  = lane & 15;
    const int quad = lane >> 4;

    const float* W = (p == 0) ? Wq : (p == 1) ? Wk : Wv;
    const float* src = W + (size_t)(c * 32 + quad * 8) * 64 + s * 16 + m16;
    bf16x8 frag;
    #pragma unroll
    for (int j = 0; j < 8; ++j) frag[j] = (__bf16)src[(size_t)j * 64];
    *(bf16x8*)(Wp + (size_t)pg * 512 + lane * 8) = frag;
}

// Kernel 1: fused QKV projection, K-split across waves.
// grid = 1024 blocks (16 rows each), block = 256 = 4 waves.
// Per kstep: 1 ds_read A-frag, then ALL 12 Wp fragments loaded into a
// register batch (12 outstanding loads), sched_barrier, then 12 MFMAs.
__global__ __launch_bounds__(256) void qkv_fused(
    const float* __restrict__ x,     // [16384][1024] fp32
    const __bf16* __restrict__ Wp,   // [384][512] fragment-packed bf16
    const float* __restrict__ bq, const float* __restrict__ bk,
    const float* __restrict__ bv,
    __bf16* __restrict__ Q, __bf16* __restrict__ K, __bf16* __restrict__ Vt)
{
    __shared__ alignas(16) unsigned char Smem[36864];  // Xs (33792) ∪ Red (36864)

    const int rt   = blockIdx.x;                  // 0..1023
    const int wave = threadIdx.x >> 6;            // K-slice owner
    const int lane = threadIdx.x & 63;
    const int m16  = lane & 15;
    const int quad = lane >> 4;
    const int row0 = rt * 16;

    __bf16* Xs = (__bf16*)(Smem + wave * 8448);   // 16 rows x 264 (pad 8)

    // ---- Phase 1: stage x-slice (16 rows x 256 cols), fp32 -> bf16 ----
    {
        const float* xsrc = x + (size_t)row0 * 1024 + wave * 256;
        const int sr = lane >> 5;                 // 0..1
        const int sc = (lane & 31) * 8;           // 0..248
        #pragma unroll
        for (int i = 0; i < 8; ++i) {
            const int r = i * 2 + sr;
            f32x4 v0 = *(const f32x4*)(xsrc + (size_t)r * 1024 + sc);
            f32x4 v1 = *(const f32x4*)(xsrc + (size_t)r * 1024 + sc + 4);
            bf16x8 w;
            #pragma unroll
            for (int e = 0; e < 4; ++e) { w[e] = (__bf16)v0[e]; w[4 + e] = (__bf16)v1[e]; }
            *(bf16x8*)&Xs[r * 264 + sc] = w;
        }
    }
    __builtin_amdgcn_wave_barrier();   // pin DS write->read order (wave-local)

    // ---- Phase 2: K-loop with batched Wp loads ----
    f32x4 acc[3][4];
    #pragma unroll
    for (int p = 0; p < 3; ++p)
        #pragma unroll
        for (int s = 0; s < 4; ++s) acc[p][s] = {0.f, 0.f, 0.f, 0.f};

    for (int k0 = 0; k0 < 256; k0 += 32) {
        bf16x8 a = *(const bf16x8*)&Xs[m16 * 264 + k0 + quad * 8];
        const int cbase = wave * 8 + (k0 >> 5);

        bf16x8 bf[12];                 // all 12 loads in flight before any use
        #pragma unroll
        for (int ps = 0; ps < 12; ++ps) {
            const int p = ps >> 2, s = ps & 3;
            bf[ps] = *(const bf16x8*)(Wp +
                ((size_t)((p * 32 + cbase) * 4 + s) << 9) + lane * 8);
        }
        __builtin_amdgcn_sched_barrier(0);   // keep loads above, MFMAs below

        #pragma unroll
        for (int ps = 0; ps < 12; ++ps)
            acc[ps >> 2][ps & 3] =
                __builtin_amdgcn_mfma_f32_16x16x32_bf16(a, bf[ps], acc[ps >> 2][ps & 3], 0, 0, 0);
    }

    // ---- Phase 3: cross-wave reduce (Red overlays dead Xs) + epilogue ----
    f32x4* Red = (f32x4*)Smem;                    // [3][12][64]
    __syncthreads();                              // all Xs reads done
    if (wave != 0) {
        #pragma unroll
        for (int p = 0; p < 3; ++p)
            #pragma unroll
            for (int s = 0; s < 4; ++s)
                Red[((wave - 1) * 12 + p * 4 + s) * 64 + lane] = acc[p][s];
    }
    __syncthreads();
    if (wave != 0) return;

    #pragma unroll
    for (int p = 0; p < 3; ++p)
        #pragma unroll
        for (int s = 0; s < 4; ++s) {
            f32x4 sum = acc[p][s];
            #pragma unroll
            for (int w = 0; w < 3; ++w) {
                f32x4 v = Red[(w * 12 + p * 4 + s) * 64 + lane];
                #pragma unroll
                for (int e = 0; e < 4; ++e) sum[e] += v[e];
            }
            acc[p][s] = sum;
        }

    // Q epilogue (p=0)
    #pragma unroll
    for (int s = 0; s < 4; ++s) {
        const int h = s * 16 + m16;
        const float bia = bq[h];
        #pragma unroll
        for (int r = 0; r < 4; ++r)
            Q[(size_t)(row0 + quad * 4 + r) * 64 + h] = (__bf16)(acc[0][s][r] + bia);
    }
    // K epilogue (p=1)
    #pragma unroll
    for (int s = 0; s < 4; ++s) {
        const int h = s * 16 + m16;
        const float bia = bk[h];
        #pragma unroll
        for (int r = 0; r < 4; ++r)
            K[(size_t)(row0 + quad * 4 + r) * 64 + h] = (__bf16)(acc[1][s][r] + bia);
    }
    // V epilogue (p=2), transposed Vt[b][h][t]
    {
        const int bidx = row0 >> 11;
        const int t0   = (row0 & 2047) + quad * 4;
        #pragma unroll
        for (int s = 0; s < 4; ++s) {
            const int h = s * 16 + m16;
            const float bia = bv[h];
            bf16x4 pack;
            #pragma unroll
            for (int r = 0; r < 4; ++r) pack[r] = (__bf16)(acc[2][s][r] + bia);
            *(bf16x4*)(Vt + (size_t)bidx * (HS_ * T_) + (size_t)h * T_ + t0) = pack;
        }
    }
}

// Kernel 2: split-K causal attention partials, S^T scheme.
// BARRIER-FREE: the old LDS staging only re-permuted K/V into fragment
// order; that permutation is folded into per-lane global addresses here.
// K/V tiles (8 KB each) are L2-resident, so frag-direct loads hit L2.
// No LDS, no __syncthreads — waves free-run, loads pipeline across tiles.
// grid = (8 key-slots, 32 q-tiles, 8 batches), block = 256 (4 waves x 16 q).
__global__ __launch_bounds__(256) void attn_partial(
    const __bf16* __restrict__ Q,   // [8][2048][64]
    const __bf16* __restrict__ K,   // [8][2048][64]
    const __bf16* __restrict__ Vt,  // [8][64][2048]
    float* __restrict__ Opart,      // [8*32*8][64][64]
    float* __restrict__ Ml)         // [8*32*8][64][2]
{
    const int z  = blockIdx.x;      // key slot 0..7
    const int qt = blockIdx.y;      // q tile 0..31
    const int b  = blockIdx.z;      // batch
    if (z > qt) return;             // uniform exit

    const int tid  = threadIdx.x;
    const int wave = tid >> 6;
    const int lane = tid & 63;
    const int m16  = lane & 15;
    const int quad = lane >> 4;

    const __bf16* Qb = Q  + (size_t)b * T_ * HS_;
    const __bf16* Kb = K  + (size_t)b * T_ * HS_;
    const __bf16* Vb = Vt + (size_t)b * HS_ * T_;

    const int q0   = qt * 64 + wave * 16;
    const int qrow = q0 + m16;                    // this lane's q row

    bf16x8 qb0 = *(const bf16x8*)(Qb + (size_t)qrow * 64 + quad * 8);
    bf16x8 qb1 = *(const bf16x8*)(Qb + (size_t)qrow * 64 + 32 + quad * 8);

    // Per-lane fragment base pointers (constant across the jt loop).
    // K A-frag (snb, i): row j0+key, elems i*32 + quad*8 .. +8
    //   key = (snb>>1)*32 + (m16>>2)*8 + (snb&1)*4 + (m16&3)
    // V A-frag (hs, i): row h = hs*16+m16 of Vt, elems j0 + i*32 + quad*8
    const __bf16* kf[4];
    #pragma unroll
    for (int snb = 0; snb < 4; ++snb) {
        const int key = ((snb >> 1) << 5) + ((m16 >> 2) << 3) + ((snb & 1) << 2) + (m16 & 3);
        kf[snb] = Kb + (size_t)key * 64 + quad * 8;
    }
    const __bf16* vf[4];
    #pragma unroll
    for (int hs = 0; hs < 4; ++hs)
        vf[hs] = Vb + (size_t)(hs * 16 + m16) * T_ + quad * 8;

    f32x4 o[4];                                   // O^T: h=hs*16+quad*4+r, q=m16
    #pragma unroll
    for (int hs = 0; hs < 4; ++hs) o[hs] = {0.f, 0.f, 0.f, 0.f};
    float m_run = -1e30f, l_run = 0.f;

    for (int jt = z; jt <= qt; jt += 8) {         // uniform trip count in block
        const int j0 = jt * 64;
        const size_t kofs = (size_t)j0 * 64;

        // all 16 fragment loads issued up front — fully independent
        bf16x8 ka0[4], ka1[4], va0[4], va1[4];
        #pragma unroll
        for (int snb = 0; snb < 4; ++snb) {
            ka0[snb] = *(const bf16x8*)(kf[snb] + kofs);
            ka1[snb] = *(const bf16x8*)(kf[snb] + kofs + 32);
        }
        #pragma unroll
        for (int hs = 0; hs < 4; ++hs) {
            va0[hs] = *(const bf16x8*)(vf[hs] + j0);
            va1[hs] = *(const bf16x8*)(vf[hs] + j0 + 32);
        }

        // S^T = K.Q^T
        f32x4 s[4];
        #pragma unroll
        for (int snb = 0; snb < 4; ++snb) s[snb] = {0.f, 0.f, 0.f, 0.f};
        #pragma unroll
        for (int snb = 0; snb < 4; ++snb) {
            s[snb] = __builtin_amdgcn_mfma_f32_16x16x32_bf16(ka0[snb], qb0, s[snb], 0, 0, 0);
            s[snb] = __builtin_amdgcn_mfma_f32_16x16x32_bf16(ka1[snb], qb1, s[snb], 0, 0, 0);
        }

        // softmax: lane holds 16 keys of q=qrow; 2+2 shuffles total
        float mx = -1e30f;
        #pragma unroll
        for (int snb = 0; snb < 4; ++snb) {
            const int kbase = j0 + ((snb >> 1) << 5) + (quad << 3) + ((snb & 1) << 2);
            #pragma unroll
            for (int r = 0; r < 4; ++r) {
                float v = s[snb][r] * 0.125f;             // 1/sqrt(64)
                v = (kbase + r <= qrow) ? v : -1e30f;     // causal (phys key)
                s[snb][r] = v;
                mx = fmaxf(mx, v);
            }
        }
        mx = fmaxf(mx, __shfl_xor(mx, 16));
        mx = fmaxf(mx, __shfl_xor(mx, 32));

        const float newm  = fmaxf(m_run, mx);
        const float alpha = __expf(m_run - newm);
        m_run = newm;

        float rs = 0.f;
        #pragma unroll
        for (int snb = 0; snb < 4; ++snb)
            #pragma unroll
            for (int r = 0; r < 4; ++r) {
                float pv = __expf(s[snb][r] - newm);
                s[snb][r] = pv;
                rs += pv;
            }
        rs += __shfl_xor(rs, 16);
        rs += __shfl_xor(rs, 32);
        l_run = l_run * alpha + rs;

        #pragma unroll
        for (int hs = 0; hs < 4; ++hs)
            #pragma unroll
            for (int r = 0; r < 4; ++r) o[hs][r] *= alpha;

        // P^T (registers) -> PV B-operand directly
        bf16x8 pb0, pb1;
        #pragma unroll
        for (int r = 0; r < 4; ++r) {
            pb0[r]     = (__bf16)s[0][r];
            pb0[4 + r] = (__bf16)s[1][r];
            pb1[r]     = (__bf16)s[2][r];
            pb1[4 + r] = (__bf16)s[3][r];
        }

        // O^T += Vt . P^T
        #pragma unroll
        for (int hs = 0; hs < 4; ++hs) {
            o[hs] = __builtin_amdgcn_mfma_f32_16x16x32_bf16(va0[hs], pb0, o[hs], 0, 0, 0);
            o[hs] = __builtin_amdgcn_mfma_f32_16x16x32_bf16(va1[hs], pb1, o[hs], 0, 0, 0);
        }
    }

    // epilogue: Opart[q][h] fp32 (16B stores), Ml per q
    const int slot = (b * 32 + qt) * 8 + z;
    float* Op = Opart + (size_t)slot * 4096;
    #pragma unroll
    for (int hs = 0; hs < 4; ++hs)
        *(f32x4*)(Op + (size_t)(wave * 16 + m16) * 64 + hs * 16 + quad * 4) = o[hs];
    if (quad == 0) {
        Ml[(size_t)slot * 128 + (wave * 16 + m16) * 2 + 0] = m_run;
        Ml[(size_t)slot * 128 + (wave * 16 + m16) * 2 + 1] = l_run;
    }
}

// Kernel 3: merge the <=8 slot-partials per q-tile (log-sum-exp weighting).
// Two-pass: slot scales from Ml first (includes the 1/den normalization),
// then 16 fully-independent f32x4 Opart loads — no serial alpha chain.
// grid = (64, 8): rows split 2-way -> 512 blocks = 2 blocks/CU.
__global__ __launch_bounds__(256) void attn_merge(
    const float* __restrict__ Opart, const float* __restrict__ Ml,
    float* __restrict__ O)
{
    const int qt  = blockIdx.x >> 1;
    const int rh  = blockIdx.x & 1;
    const int b   = blockIdx.y;
    const int tid = threadIdx.x;
    const int row = rh * 32 + (tid >> 3);     // 0..63
    const int cb  = tid & 7;                  // 8-col chunk
    const int nc  = (qt + 1 < 8) ? qt + 1 : 8;
    const int slotBase = (b * 32 + qt) * 8;

    // pass A: scales. Clamped index keeps the unroll straight-line with
    // compile-time register indexing (no scratch); sc[c]=0 kills duplicates.
    float m[8], l[8], sc[8];
    #pragma unroll
    for (int c = 0; c < 8; ++c) {
        const int cc = (c < nc) ? c : nc - 1;
        const float* mlp = Ml + (size_t)(slotBase + cc) * 128 + row * 2;
        m[c] = mlp[0];
        l[c] = (c < nc) ? mlp[1] : 0.f;
    }
    float M = m[0];
    #pragma unroll
    for (int c = 1; c < 8; ++c) M = fmaxf(M, m[c]);
    float den = 0.f;
    #pragma unroll
    for (int c = 0; c < 8; ++c) {
        sc[c] = (c < nc) ? __expf(m[c] - M) : 0.f;
        den += sc[c] * l[c];
    }
    const float inv = 1.f / den;
    #pragma unroll
    for (int c = 0; c < 8; ++c) sc[c] *= inv;

    // pass B: 16 independent loads, dependency-free accumulation
    f32x4 a0 = {0.f, 0.f, 0.f, 0.f}, a1 = {0.f, 0.f, 0.f, 0.f};
    #pragma unroll
    for (int c = 0; c < 8; ++c) {
        const int cc = (c < nc) ? c : nc - 1;
        const float* op = Opart + (size_t)(slotBase + cc) * 4096 + row * 64 + cb * 8;
        f32x4 v0 = *(const f32x4*)op;
        f32x4 v1 = *(const f32x4*)(op + 4);
        #pragma unroll
        for (int e = 0; e < 4; ++e) { a0[e] += sc[c] * v0[e]; a1[e] += sc[c] * v1[e]; }
    }

    float* out = O + ((size_t)b * T_ + qt * 64 + row) * 64 + cb * 8;
    *(f32x4*)out       = a0;
    *(f32x4*)(out + 4) = a1;
}

// ---------------------------------------------------------------------------
extern "C" void kernel_launch(void* const* d_in, const int* in_sizes, int n_in,
                              void* d_out, int out_size, void* d_ws, size_t ws_size,
                              hipStream_t stream)
{
    const float* x  = (const float*)d_in[0];
    const float* Wq = (const float*)d_in[1];
    const float* bq = (const float*)d_in[2];
    const float* Wk = (const float*)d_in[3];
    const float* bk = (const float*)d_in[4];
    const float* Wv = (const float*)d_in[5];
    const float* bv = (const float*)d_in[6];
    float* out = (float*)d_out;

    __bf16* Wp = (__bf16*)d_ws;              // 384*512 bf16         = 0.4 MB
    __bf16* Q  = Wp + 384 * 512;             // 8*2048*64 bf16       = 2 MB
    __bf16* K  = Q  + (size_t)B_ * T_ * HS_;
    __bf16* Vt = K  + (size_t)B_ * T_ * HS_; // transposed [b][h][t]
    float* Opart = (float*)(Vt + (size_t)B_ * T_ * HS_);  // 2048*4096 f32 = 33.6 MB
    float* Ml    = Opart + (size_t)2048 * 4096;           // 2048*128  f32 =  1 MB

    pack_w<<<96, 256, 0, stream>>>(Wq, Wk, Wv, Wp);
    qkv_fused<<<1024, 256, 0, stream>>>(x, Wp, bq, bk, bv, Q, K, Vt);
    attn_partial<<<dim3(8, 32, 8), 256, 0, stream>>>(Q, K, Vt, Opart, Ml);
    attn_merge<<<dim3(64, 8), 256, 0, stream>>>(Opart, Ml, out);
}

// Round 3
// 173.531 us; speedup vs baseline: 1.0068x; 1.0068x over previous
//
#include <hip/hip_runtime.h>
#include <hip/hip_bf16.h>

typedef __bf16 bf16x8 __attribute__((ext_vector_type(8)));
typedef __bf16 bf16x4 __attribute__((ext_vector_type(4)));
typedef float  f32x4  __attribute__((ext_vector_type(4)));

#define B_  8
#define T_  2048
#define D_  1024
#define HS_ 64

// ---------------------------------------------------------------------------
// fp32 inputs/outputs; bf16 MFMA internally.
// pack_w -> qkv_fused -> attn_partial (frag-direct loads, PING-PONG PREFETCH)
//        -> attn_merge (two-pass).
//
// Round-12 post-mortem: barrier-free attn was 2x SLOWER (54us, VGPR=56) --
// compiler sank the 16-load batch down to uses => ~8 serial L2 round-trips
// per tile. Fix: statically-named A/B register buffers, manual 4-stage
// unroll (trip<=4), issue next tile's loads between QK^T and softmax,
// sched_barrier(0) fences. One vmcnt wait per stage; prologue latency only.
// ---------------------------------------------------------------------------

// Kernel 0: pack the three [D,HS] fp32 weights into bf16 MFMA-fragment order.
__global__ __launch_bounds__(256) void pack_w(
    const float* __restrict__ Wq, const float* __restrict__ Wk,
    const float* __restrict__ Wv, __bf16* __restrict__ Wp)
{
    const int t    = blockIdx.x * 256 + threadIdx.x;   // 0..24575
    const int lane = t & 63;
    const int pg   = t >> 6;                           // 0..383
    const int s    = pg & 3;
    const int c    = (pg >> 2) & 31;
    const int p    = pg >> 7;
    const int m16  = lane & 15;
    const int quad = lane >> 4;

    const float* W = (p == 0) ? Wq : (p == 1) ? Wk : Wv;
    const float* src = W + (size_t)(c * 32 + quad * 8) * 64 + s * 16 + m16;
    bf16x8 frag;
    #pragma unroll
    for (int j = 0; j < 8; ++j) frag[j] = (__bf16)src[(size_t)j * 64];
    *(bf16x8*)(Wp + (size_t)pg * 512 + lane * 8) = frag;
}

// Kernel 1: fused QKV projection, K-split across waves.
__global__ __launch_bounds__(256) void qkv_fused(
    const float* __restrict__ x,     // [16384][1024] fp32
    const __bf16* __restrict__ Wp,   // [384][512] fragment-packed bf16
    const float* __restrict__ bq, const float* __restrict__ bk,
    const float* __restrict__ bv,
    __bf16* __restrict__ Q, __bf16* __restrict__ K, __bf16* __restrict__ Vt)
{
    __shared__ alignas(16) unsigned char Smem[36864];  // Xs (33792) ∪ Red (36864)

    const int rt   = blockIdx.x;                  // 0..1023
    const int wave = threadIdx.x >> 6;            // K-slice owner
    const int lane = threadIdx.x & 63;
    const int m16  = lane & 15;
    const int quad = lane >> 4;
    const int row0 = rt * 16;

    __bf16* Xs = (__bf16*)(Smem + wave * 8448);   // 16 rows x 264 (pad 8)

    // ---- Phase 1: stage x-slice (16 rows x 256 cols), fp32 -> bf16 ----
    {
        const float* xsrc = x + (size_t)row0 * 1024 + wave * 256;
        const int sr = lane >> 5;                 // 0..1
        const int sc = (lane & 31) * 8;           // 0..248
        #pragma unroll
        for (int i = 0; i < 8; ++i) {
            const int r = i * 2 + sr;
            f32x4 v0 = *(const f32x4*)(xsrc + (size_t)r * 1024 + sc);
            f32x4 v1 = *(const f32x4*)(xsrc + (size_t)r * 1024 + sc + 4);
            bf16x8 w;
            #pragma unroll
            for (int e = 0; e < 4; ++e) { w[e] = (__bf16)v0[e]; w[4 + e] = (__bf16)v1[e]; }
            *(bf16x8*)&Xs[r * 264 + sc] = w;
        }
    }
    __builtin_amdgcn_wave_barrier();   // pin DS write->read order (wave-local)

    // ---- Phase 2: K-loop with batched Wp loads ----
    f32x4 acc[3][4];
    #pragma unroll
    for (int p = 0; p < 3; ++p)
        #pragma unroll
        for (int s = 0; s < 4; ++s) acc[p][s] = {0.f, 0.f, 0.f, 0.f};

    for (int k0 = 0; k0 < 256; k0 += 32) {
        bf16x8 a = *(const bf16x8*)&Xs[m16 * 264 + k0 + quad * 8];
        const int cbase = wave * 8 + (k0 >> 5);

        bf16x8 bf[12];                 // all 12 loads in flight before any use
        #pragma unroll
        for (int ps = 0; ps < 12; ++ps) {
            const int p = ps >> 2, s = ps & 3;
            bf[ps] = *(const bf16x8*)(Wp +
                ((size_t)((p * 32 + cbase) * 4 + s) << 9) + lane * 8);
        }
        __builtin_amdgcn_sched_barrier(0);   // keep loads above, MFMAs below

        #pragma unroll
        for (int ps = 0; ps < 12; ++ps)
            acc[ps >> 2][ps & 3] =
                __builtin_amdgcn_mfma_f32_16x16x32_bf16(a, bf[ps], acc[ps >> 2][ps & 3], 0, 0, 0);
    }

    // ---- Phase 3: cross-wave reduce (Red overlays dead Xs) + epilogue ----
    f32x4* Red = (f32x4*)Smem;                    // [3][12][64]
    __syncthreads();                              // all Xs reads done
    if (wave != 0) {
        #pragma unroll
        for (int p = 0; p < 3; ++p)
            #pragma unroll
            for (int s = 0; s < 4; ++s)
                Red[((wave - 1) * 12 + p * 4 + s) * 64 + lane] = acc[p][s];
    }
    __syncthreads();
    if (wave != 0) return;

    #pragma unroll
    for (int p = 0; p < 3; ++p)
        #pragma unroll
        for (int s = 0; s < 4; ++s) {
            f32x4 sum = acc[p][s];
            #pragma unroll
            for (int w = 0; w < 3; ++w) {
                f32x4 v = Red[(w * 12 + p * 4 + s) * 64 + lane];
                #pragma unroll
                for (int e = 0; e < 4; ++e) sum[e] += v[e];
            }
            acc[p][s] = sum;
        }

    // Q epilogue (p=0)
    #pragma unroll
    for (int s = 0; s < 4; ++s) {
        const int h = s * 16 + m16;
        const float bia = bq[h];
        #pragma unroll
        for (int r = 0; r < 4; ++r)
            Q[(size_t)(row0 + quad * 4 + r) * 64 + h] = (__bf16)(acc[0][s][r] + bia);
    }
    // K epilogue (p=1)
    #pragma unroll
    for (int s = 0; s < 4; ++s) {
        const int h = s * 16 + m16;
        const float bia = bk[h];
        #pragma unroll
        for (int r = 0; r < 4; ++r)
            K[(size_t)(row0 + quad * 4 + r) * 64 + h] = (__bf16)(acc[1][s][r] + bia);
    }
    // V epilogue (p=2), transposed Vt[b][h][t]
    {
        const int bidx = row0 >> 11;
        const int t0   = (row0 & 2047) + quad * 4;
        #pragma unroll
        for (int s = 0; s < 4; ++s) {
            const int h = s * 16 + m16;
            const float bia = bv[h];
            bf16x4 pack;
            #pragma unroll
            for (int r = 0; r < 4; ++r) pack[r] = (__bf16)(acc[2][s][r] + bia);
            *(bf16x4*)(Vt + (size_t)bidx * (HS_ * T_) + (size_t)h * T_ + t0) = pack;
        }
    }
}

// Kernel 2: split-K causal attention partials, S^T scheme.
// Frag-direct loads (verified correct in R2) + ping-pong register prefetch.
// grid = (8 key-slots, 32 q-tiles, 8 batches), block = 256 (4 waves x 16 q).
// Trip count <= 4, manually unrolled; buffers statically named (no scratch).
__global__ __launch_bounds__(256, 2) void attn_partial(
    const __bf16* __restrict__ Q,   // [8][2048][64]
    const __bf16* __restrict__ K,   // [8][2048][64]
    const __bf16* __restrict__ Vt,  // [8][64][2048]
    float* __restrict__ Opart,      // [8*32*8][64][64]
    float* __restrict__ Ml)         // [8*32*8][64][2]
{
    const int z  = blockIdx.x;      // key slot 0..7
    const int qt = blockIdx.y;      // q tile 0..31
    const int b  = blockIdx.z;      // batch
    if (z > qt) return;             // uniform exit

    const int tid  = threadIdx.x;
    const int wave = tid >> 6;
    const int lane = tid & 63;
    const int m16  = lane & 15;
    const int quad = lane >> 4;

    const __bf16* Qb = Q  + (size_t)b * T_ * HS_;
    const __bf16* Kb = K  + (size_t)b * T_ * HS_;
    const __bf16* Vb = Vt + (size_t)b * HS_ * T_;

    const int q0   = qt * 64 + wave * 16;
    const int qrow = q0 + m16;                    // this lane's q row

    bf16x8 qb0 = *(const bf16x8*)(Qb + (size_t)qrow * 64 + quad * 8);
    bf16x8 qb1 = *(const bf16x8*)(Qb + (size_t)qrow * 64 + 32 + quad * 8);

    // Per-lane fragment base pointers (constant across stages).
    // K A-frag (snb, i): row j0+key, elems i*32 + quad*8 .. +8
    //   key = (snb>>1)*32 + (m16>>2)*8 + (snb&1)*4 + (m16&3)
    // V A-frag (hs, i): row h = hs*16+m16 of Vt, elems j0 + i*32 + quad*8
    const __bf16* kf[4];
    #pragma unroll
    for (int snb = 0; snb < 4; ++snb) {
        const int key = ((snb >> 1) << 5) + ((m16 >> 2) << 3) + ((snb & 1) << 2) + (m16 & 3);
        kf[snb] = Kb + (size_t)key * 64 + quad * 8;
    }
    const __bf16* vf[4];
    #pragma unroll
    for (int hs = 0; hs < 4; ++hs)
        vf[hs] = Vb + (size_t)(hs * 16 + m16) * T_ + quad * 8;

    f32x4 o[4];                                   // O^T: h=hs*16+quad*4+r, q=m16
    #pragma unroll
    for (int hs = 0; hs < 4; ++hs) o[hs] = {0.f, 0.f, 0.f, 0.f};
    float m_run = -1e30f, l_run = 0.f;

    // Ping-pong register tile buffers (statically named -> no scratch).
    bf16x8 kA0[4], kA1[4], vA0[4], vA1[4];
    bf16x8 kB0[4], kB1[4], vB0[4], vB1[4];

#define LOADT(K0v, K1v, V0v, V1v, J0)                                     \
    {                                                                     \
        const int j0_ = (J0);                                             \
        const size_t kofs_ = (size_t)j0_ * 64;                            \
        _Pragma("unroll")                                                 \
        for (int sn_ = 0; sn_ < 4; ++sn_) {                               \
            K0v[sn_] = *(const bf16x8*)(kf[sn_] + kofs_);                 \
            K1v[sn_] = *(const bf16x8*)(kf[sn_] + kofs_ + 32);            \
        }                                                                 \
        _Pragma("unroll")                                                 \
        for (int hs_ = 0; hs_ < 4; ++hs_) {                               \
            V0v[hs_] = *(const bf16x8*)(vf[hs_] + j0_);                   \
            V1v[hs_] = *(const bf16x8*)(vf[hs_] + j0_ + 32);              \
        }                                                                 \
    }

#define STAGE(CK0, CK1, CV0, CV1, NK0, NK1, NV0, NV1)                     \
    {                                                                     \
        const int j0 = jt * 64;                                           \
        f32x4 s[4];                                                       \
        _Pragma("unroll")                                                 \
        for (int sn_ = 0; sn_ < 4; ++sn_) {                               \
            s[sn_] = {0.f, 0.f, 0.f, 0.f};                                \
            s[sn_] = __builtin_amdgcn_mfma_f32_16x16x32_bf16(CK0[sn_], qb0, s[sn_], 0, 0, 0); \
            s[sn_] = __builtin_amdgcn_mfma_f32_16x16x32_bf16(CK1[sn_], qb1, s[sn_], 0, 0, 0); \
        }                                                                 \
        /* prefetch next tile while softmax+PV run */                     \
        if (jt + 8 <= qt) LOADT(NK0, NK1, NV0, NV1, j0 + 512);            \
        __builtin_amdgcn_sched_barrier(0);                                \
        float mx = -1e30f;                                                \
        _Pragma("unroll")                                                 \
        for (int sn_ = 0; sn_ < 4; ++sn_) {                               \
            const int kbase = j0 + ((sn_ >> 1) << 5) + (quad << 3) + ((sn_ & 1) << 2); \
            _Pragma("unroll")                                             \
            for (int r_ = 0; r_ < 4; ++r_) {                              \
                float v_ = s[sn_][r_] * 0.125f;                           \
                v_ = (kbase + r_ <= qrow) ? v_ : -1e30f;                  \
                s[sn_][r_] = v_;                                          \
                mx = fmaxf(mx, v_);                                       \
            }                                                             \
        }                                                                 \
        mx = fmaxf(mx, __shfl_xor(mx, 16));                               \
        mx = fmaxf(mx, __shfl_xor(mx, 32));                               \
        const float newm  = fmaxf(m_run, mx);                             \
        const float alpha = __expf(m_run - newm);                         \
        m_run = newm;                                                     \
        float rs = 0.f;                                                   \
        _Pragma("unroll")                                                 \
        for (int sn_ = 0; sn_ < 4; ++sn_)                                 \
            _Pragma("unroll")                                             \
            for (int r_ = 0; r_ < 4; ++r_) {                              \
                float pv_ = __expf(s[sn_][r_] - newm);                    \
                s[sn_][r_] = pv_;                                         \
                rs += pv_;                                                \
            }                                                             \
        rs += __shfl_xor(rs, 16);                                         \
        rs += __shfl_xor(rs, 32);                                         \
        l_run = l_run * alpha + rs;                                       \
        _Pragma("unroll")                                                 \
        for (int hs_ = 0; hs_ < 4; ++hs_)                                 \
            _Pragma("unroll")                                             \
            for (int r_ = 0; r_ < 4; ++r_) o[hs_][r_] *= alpha;           \
        bf16x8 pb0, pb1;                                                  \
        _Pragma("unroll")                                                 \
        for (int r_ = 0; r_ < 4; ++r_) {                                  \
            pb0[r_]     = (__bf16)s[0][r_];                               \
            pb0[4 + r_] = (__bf16)s[1][r_];                               \
            pb1[r_]     = (__bf16)s[2][r_];                               \
            pb1[4 + r_] = (__bf16)s[3][r_];                               \
        }                                                                 \
        _Pragma("unroll")                                                 \
        for (int hs_ = 0; hs_ < 4; ++hs_) {                               \
            o[hs_] = __builtin_amdgcn_mfma_f32_16x16x32_bf16(CV0[hs_], pb0, o[hs_], 0, 0, 0); \
            o[hs_] = __builtin_amdgcn_mfma_f32_16x16x32_bf16(CV1[hs_], pb1, o[hs_], 0, 0, 0); \
        }                                                                 \
    }

    // Prologue: load tile z into A. Trip count = floor((qt-z)/8)+1 <= 4.
    int jt = z;
    LOADT(kA0, kA1, vA0, vA1, z * 64);
    STAGE(kA0, kA1, vA0, vA1, kB0, kB1, vB0, vB1);
    jt += 8;
    if (jt <= qt) {
        STAGE(kB0, kB1, vB0, vB1, kA0, kA1, vA0, vA1);
        jt += 8;
        if (jt <= qt) {
            STAGE(kA0, kA1, vA0, vA1, kB0, kB1, vB0, vB1);
            jt += 8;
            if (jt <= qt) {
                STAGE(kB0, kB1, vB0, vB1, kA0, kA1, vA0, vA1);
            }
        }
    }
#undef STAGE
#undef LOADT

    // epilogue: Opart[q][h] fp32 (16B stores), Ml per q
    const int slot = (b * 32 + qt) * 8 + z;
    float* Op = Opart + (size_t)slot * 4096;
    #pragma unroll
    for (int hs = 0; hs < 4; ++hs)
        *(f32x4*)(Op + (size_t)(wave * 16 + m16) * 64 + hs * 16 + quad * 4) = o[hs];
    if (quad == 0) {
        Ml[(size_t)slot * 128 + (wave * 16 + m16) * 2 + 0] = m_run;
        Ml[(size_t)slot * 128 + (wave * 16 + m16) * 2 + 1] = l_run;
    }
}

// Kernel 3: merge the <=8 slot-partials per q-tile (log-sum-exp weighting).
// Two-pass: slot scales from Ml first (includes the 1/den normalization),
// then 16 fully-independent f32x4 Opart loads — no serial alpha chain.
// grid = (64, 8): rows split 2-way -> 512 blocks = 2 blocks/CU.
__global__ __launch_bounds__(256) void attn_merge(
    const float* __restrict__ Opart, const float* __restrict__ Ml,
    float* __restrict__ O)
{
    const int qt  = blockIdx.x >> 1;
    const int rh  = blockIdx.x & 1;
    const int b   = blockIdx.y;
    const int tid = threadIdx.x;
    const int row = rh * 32 + (tid >> 3);     // 0..63
    const int cb  = tid & 7;                  // 8-col chunk
    const int nc  = (qt + 1 < 8) ? qt + 1 : 8;
    const int slotBase = (b * 32 + qt) * 8;

    // pass A: scales. Clamped index keeps the unroll straight-line with
    // compile-time register indexing (no scratch); sc[c]=0 kills duplicates.
    float m[8], l[8], sc[8];
    #pragma unroll
    for (int c = 0; c < 8; ++c) {
        const int cc = (c < nc) ? c : nc - 1;
        const float* mlp = Ml + (size_t)(slotBase + cc) * 128 + row * 2;
        m[c] = mlp[0];
        l[c] = (c < nc) ? mlp[1] : 0.f;
    }
    float M = m[0];
    #pragma unroll
    for (int c = 1; c < 8; ++c) M = fmaxf(M, m[c]);
    float den = 0.f;
    #pragma unroll
    for (int c = 0; c < 8; ++c) {
        sc[c] = (c < nc) ? __expf(m[c] - M) : 0.f;
        den += sc[c] * l[c];
    }
    const float inv = 1.f / den;
    #pragma unroll
    for (int c = 0; c < 8; ++c) sc[c] *= inv;

    // pass B: 16 independent loads, dependency-free accumulation
    f32x4 a0 = {0.f, 0.f, 0.f, 0.f}, a1 = {0.f, 0.f, 0.f, 0.f};
    #pragma unroll
    for (int c = 0; c < 8; ++c) {
        const int cc = (c < nc) ? c : nc - 1;
        const float* op = Opart + (size_t)(slotBase + cc) * 4096 + row * 64 + cb * 8;
        f32x4 v0 = *(const f32x4*)op;
        f32x4 v1 = *(const f32x4*)(op + 4);
        #pragma unroll
        for (int e = 0; e < 4; ++e) { a0[e] += sc[c] * v0[e]; a1[e] += sc[c] * v1[e]; }
    }

    float* out = O + ((size_t)b * T_ + qt * 64 + row) * 64 + cb * 8;
    *(f32x4*)out       = a0;
    *(f32x4*)(out + 4) = a1;
}

// ---------------------------------------------------------------------------
extern "C" void kernel_launch(void* const* d_in, const int* in_sizes, int n_in,
                              void* d_out, int out_size, void* d_ws, size_t ws_size,
                              hipStream_t stream)
{
    const float* x  = (const float*)d_in[0];
    const float* Wq = (const float*)d_in[1];
    const float* bq = (const float*)d_in[2];
    const float* Wk = (const float*)d_in[3];
    const float* bk = (const float*)d_in[4];
    const float* Wv = (const float*)d_in[5];
    const float* bv = (const float*)d_in[6];
    float* out = (float*)d_out;

    __bf16* Wp = (__bf16*)d_ws;              // 384*512 bf16         = 0.4 MB
    __bf16* Q  = Wp + 384 * 512;             // 8*2048*64 bf16       = 2 MB
    __bf16* K  = Q  + (size_t)B_ * T_ * HS_;
    __bf16* Vt = K  + (size_t)B_ * T_ * HS_; // transposed [b][h][t]
    float* Opart = (float*)(Vt + (size_t)B_ * T_ * HS_);  // 2048*4096 f32 = 33.6 MB
    float* Ml    = Opart + (size_t)2048 * 4096;           // 2048*128  f32 =  1 MB

    pack_w<<<96, 256, 0, stream>>>(Wq, Wk, Wv, Wp);
    qkv_fused<<<1024, 256, 0, stream>>>(x, Wp, bq, bk, bv, Q, K, Vt);
    attn_partial<<<dim3(8, 32, 8), 256, 0, stream>>>(Q, K, Vt, Opart, Ml);
    attn_merge<<<dim3(64, 8), 256, 0, stream>>>(Opart, Ml, out);
}

// Round 4
// 158.177 us; speedup vs baseline: 1.1045x; 1.0971x over previous
//
#include <hip/hip_runtime.h>
#include <hip/hip_bf16.h>

typedef __bf16 bf16x8 __attribute__((ext_vector_type(8)));
typedef __bf16 bf16x4 __attribute__((ext_vector_type(4)));
typedef float  f32x4  __attribute__((ext_vector_type(4)));

#define B_  8
#define T_  2048
#define D_  1024
#define HS_ 64

// ---------------------------------------------------------------------------
// fp32 inputs/outputs; bf16 MFMA internally.
// pack_w -> qkv_fused -> attn_fused (single-pass, coalesced LDS staging,
//                                    reg-prefetch, direct O write).
//
// Round-13 post-mortem: frag-direct global loads are 16-line gathers; TA
// processes scattered lanes ~1 line/cy => 54us regardless of schedule
// (R2 sunk-loads == R3 ping-pong). Coalesced staging is mandatory.
// This round: revert to the R0-verified staged tile loop, but delete
// split-K + Opart + merge entirely (grid 32x8, jt=0..qt per block),
// with next-tile loads reg-prefetched under compute (T14).
// ---------------------------------------------------------------------------

// Kernel 0: pack the three [D,HS] fp32 weights into bf16 MFMA-fragment order.
__global__ __launch_bounds__(256) void pack_w(
    const float* __restrict__ Wq, const float* __restrict__ Wk,
    const float* __restrict__ Wv, __bf16* __restrict__ Wp)
{
    const int t    = blockIdx.x * 256 + threadIdx.x;   // 0..24575
    const int lane = t & 63;
    const int pg   = t >> 6;                           // 0..383
    const int s    = pg & 3;
    const int c    = (pg >> 2) & 31;
    const int p    = pg >> 7;
    const int m16  = lane & 15;
    const int quad = lane >> 4;

    const float* W = (p == 0) ? Wq : (p == 1) ? Wk : Wv;
    const float* src = W + (size_t)(c * 32 + quad * 8) * 64 + s * 16 + m16;
    bf16x8 frag;
    #pragma unroll
    for (int j = 0; j < 8; ++j) frag[j] = (__bf16)src[(size_t)j * 64];
    *(bf16x8*)(Wp + (size_t)pg * 512 + lane * 8) = frag;
}

// Kernel 1: fused QKV projection, K-split across waves.
__global__ __launch_bounds__(256) void qkv_fused(
    const float* __restrict__ x,     // [16384][1024] fp32
    const __bf16* __restrict__ Wp,   // [384][512] fragment-packed bf16
    const float* __restrict__ bq, const float* __restrict__ bk,
    const float* __restrict__ bv,
    __bf16* __restrict__ Q, __bf16* __restrict__ K, __bf16* __restrict__ Vt)
{
    __shared__ alignas(16) unsigned char Smem[36864];  // Xs (33792) ∪ Red (36864)

    const int rt   = blockIdx.x;                  // 0..1023
    const int wave = threadIdx.x >> 6;            // K-slice owner
    const int lane = threadIdx.x & 63;
    const int m16  = lane & 15;
    const int quad = lane >> 4;
    const int row0 = rt * 16;

    __bf16* Xs = (__bf16*)(Smem + wave * 8448);   // 16 rows x 264 (pad 8)

    // ---- Phase 1: stage x-slice (16 rows x 256 cols), fp32 -> bf16 ----
    {
        const float* xsrc = x + (size_t)row0 * 1024 + wave * 256;
        const int sr = lane >> 5;                 // 0..1
        const int sc = (lane & 31) * 8;           // 0..248
        #pragma unroll
        for (int i = 0; i < 8; ++i) {
            const int r = i * 2 + sr;
            f32x4 v0 = *(const f32x4*)(xsrc + (size_t)r * 1024 + sc);
            f32x4 v1 = *(const f32x4*)(xsrc + (size_t)r * 1024 + sc + 4);
            bf16x8 w;
            #pragma unroll
            for (int e = 0; e < 4; ++e) { w[e] = (__bf16)v0[e]; w[4 + e] = (__bf16)v1[e]; }
            *(bf16x8*)&Xs[r * 264 + sc] = w;
        }
    }
    __builtin_amdgcn_wave_barrier();   // pin DS write->read order (wave-local)

    // ---- Phase 2: K-loop with batched Wp loads ----
    f32x4 acc[3][4];
    #pragma unroll
    for (int p = 0; p < 3; ++p)
        #pragma unroll
        for (int s = 0; s < 4; ++s) acc[p][s] = {0.f, 0.f, 0.f, 0.f};

    for (int k0 = 0; k0 < 256; k0 += 32) {
        bf16x8 a = *(const bf16x8*)&Xs[m16 * 264 + k0 + quad * 8];
        const int cbase = wave * 8 + (k0 >> 5);

        bf16x8 bf[12];                 // all 12 loads in flight before any use
        #pragma unroll
        for (int ps = 0; ps < 12; ++ps) {
            const int p = ps >> 2, s = ps & 3;
            bf[ps] = *(const bf16x8*)(Wp +
                ((size_t)((p * 32 + cbase) * 4 + s) << 9) + lane * 8);
        }
        __builtin_amdgcn_sched_barrier(0);   // keep loads above, MFMAs below

        #pragma unroll
        for (int ps = 0; ps < 12; ++ps)
            acc[ps >> 2][ps & 3] =
                __builtin_amdgcn_mfma_f32_16x16x32_bf16(a, bf[ps], acc[ps >> 2][ps & 3], 0, 0, 0);
    }

    // ---- Phase 3: cross-wave reduce (Red overlays dead Xs) + epilogue ----
    f32x4* Red = (f32x4*)Smem;                    // [3][12][64]
    __syncthreads();                              // all Xs reads done
    if (wave != 0) {
        #pragma unroll
        for (int p = 0; p < 3; ++p)
            #pragma unroll
            for (int s = 0; s < 4; ++s)
                Red[((wave - 1) * 12 + p * 4 + s) * 64 + lane] = acc[p][s];
    }
    __syncthreads();
    if (wave != 0) return;

    #pragma unroll
    for (int p = 0; p < 3; ++p)
        #pragma unroll
        for (int s = 0; s < 4; ++s) {
            f32x4 sum = acc[p][s];
            #pragma unroll
            for (int w = 0; w < 3; ++w) {
                f32x4 v = Red[(w * 12 + p * 4 + s) * 64 + lane];
                #pragma unroll
                for (int e = 0; e < 4; ++e) sum[e] += v[e];
            }
            acc[p][s] = sum;
        }

    // Q epilogue (p=0)
    #pragma unroll
    for (int s = 0; s < 4; ++s) {
        const int h = s * 16 + m16;
        const float bia = bq[h];
        #pragma unroll
        for (int r = 0; r < 4; ++r)
            Q[(size_t)(row0 + quad * 4 + r) * 64 + h] = (__bf16)(acc[0][s][r] + bia);
    }
    // K epilogue (p=1)
    #pragma unroll
    for (int s = 0; s < 4; ++s) {
        const int h = s * 16 + m16;
        const float bia = bk[h];
        #pragma unroll
        for (int r = 0; r < 4; ++r)
            K[(size_t)(row0 + quad * 4 + r) * 64 + h] = (__bf16)(acc[1][s][r] + bia);
    }
    // V epilogue (p=2), transposed Vt[b][h][t]
    {
        const int bidx = row0 >> 11;
        const int t0   = (row0 & 2047) + quad * 4;
        #pragma unroll
        for (int s = 0; s < 4; ++s) {
            const int h = s * 16 + m16;
            const float bia = bv[h];
            bf16x4 pack;
            #pragma unroll
            for (int r = 0; r < 4; ++r) pack[r] = (__bf16)(acc[2][s][r] + bia);
            *(bf16x4*)(Vt + (size_t)bidx * (HS_ * T_) + (size_t)h * T_ + t0) = pack;
        }
    }
}

// Kernel 2: single-pass causal attention. grid = (32 q-tiles, 8 batches),
// block = 256 (4 waves x 16 q rows). Per q-tile, loop jt=0..qt over 64-key
// tiles with the R0-verified coalesced staging (16B/thread x2 for K and V),
// next tile reg-prefetched under compute. Output written directly (no
// split-K partials, no merge kernel).
__global__ __launch_bounds__(256) void attn_fused(
    const __bf16* __restrict__ Q,   // [8][2048][64]
    const __bf16* __restrict__ K,   // [8][2048][64]
    const __bf16* __restrict__ Vt,  // [8][64][2048]
    float* __restrict__ O)          // [8][2048][64] fp32
{
    __shared__ alignas(16) __bf16 Klds[8 * 512];   // 8 frag-groups x 1KB
    __shared__ alignas(16) __bf16 Vlds[8 * 512];

    const int qt = blockIdx.x;      // q tile 0..31
    const int b  = blockIdx.y;      // batch

    const int tid  = threadIdx.x;
    const int wave = tid >> 6;
    const int lane = tid & 63;
    const int m16  = lane & 15;
    const int quad = lane >> 4;

    const __bf16* Qb = Q  + (size_t)b * T_ * HS_;
    const __bf16* Kb = K  + (size_t)b * T_ * HS_;
    const __bf16* Vb = Vt + (size_t)b * HS_ * T_;

    const int q0   = qt * 64 + wave * 16;
    const int qrow = q0 + m16;                    // this lane's q row

    bf16x8 qb0 = *(const bf16x8*)(Qb + (size_t)qrow * 64 + quad * 8);
    bf16x8 qb1 = *(const bf16x8*)(Qb + (size_t)qrow * 64 + 32 + quad * 8);

    // Per-thread staging constants (two 16B pieces each for K and V).
    // piece p = i*256 + tid: trow = p>>3 (key row in tile), tcol = p&7.
    int koffL[2], voffL[2];
    const __bf16* kgb[2];
    const __bf16* vgb[2];
    #pragma unroll
    for (int i = 0; i < 2; ++i) {
        const int p    = i * 256 + tid;
        const int trow = p >> 3;
        const int tcol = p & 7;
        const int snb  = ((trow >> 5) << 1) | ((trow >> 2) & 1);
        const int mk   = (((trow >> 3) & 3) << 2) | (trow & 3);
        koffL[i] = ((((snb << 1) | (tcol >> 2)) << 6) + (tcol & 3) * 16 + mk) * 8;
        voffL[i] = (((((trow >> 4) << 1) | (tcol >> 2)) << 6) + (tcol & 3) * 16 + (trow & 15)) * 8;
        kgb[i] = Kb + (size_t)trow * 64 + tcol * 8;   // + j0*64 per tile
        vgb[i] = Vb + (size_t)trow * T_ + tcol * 8;   // + j0    per tile
    }

    f32x4 o[4];                                   // O^T: h=hs*16+quad*4+r, q=m16
    #pragma unroll
    for (int hs = 0; hs < 4; ++hs) o[hs] = {0.f, 0.f, 0.f, 0.f};
    float m_run = -1e30f, l_run = 0.f;

    // Prologue: tile 0 into staging registers (coalesced 16B loads).
    bf16x8 kr0 = *(const bf16x8*)(kgb[0]);
    bf16x8 kr1 = *(const bf16x8*)(kgb[1]);
    bf16x8 vr0 = *(const bf16x8*)(vgb[0]);
    bf16x8 vr1 = *(const bf16x8*)(vgb[1]);

    for (int jt = 0; jt <= qt; ++jt) {
        const int j0 = jt * 64;

        __syncthreads();               // prior tile's LDS reads complete
        *(bf16x8*)&Klds[koffL[0]] = kr0;
        *(bf16x8*)&Klds[koffL[1]] = kr1;
        *(bf16x8*)&Vlds[voffL[0]] = vr0;
        *(bf16x8*)&Vlds[voffL[1]] = vr1;
        __syncthreads();               // staged tile visible

        // reg-prefetch next tile; latency hides under this tile's compute
        if (jt < qt) {
            const size_t nk = (size_t)(j0 + 64) * 64;
            kr0 = *(const bf16x8*)(kgb[0] + nk);
            kr1 = *(const bf16x8*)(kgb[1] + nk);
            vr0 = *(const bf16x8*)(vgb[0] + j0 + 64);
            vr1 = *(const bf16x8*)(vgb[1] + j0 + 64);
        }
        __builtin_amdgcn_sched_barrier(0);   // loads issue above compute

        // S^T = K.Q^T
        f32x4 s[4];
        #pragma unroll
        for (int snb = 0; snb < 4; ++snb) s[snb] = {0.f, 0.f, 0.f, 0.f};
        #pragma unroll
        for (int snb = 0; snb < 4; ++snb) {
            bf16x8 ka0 = *(const bf16x8*)&Klds[((snb * 2 + 0) * 64 + lane) * 8];
            bf16x8 ka1 = *(const bf16x8*)&Klds[((snb * 2 + 1) * 64 + lane) * 8];
            s[snb] = __builtin_amdgcn_mfma_f32_16x16x32_bf16(ka0, qb0, s[snb], 0, 0, 0);
            s[snb] = __builtin_amdgcn_mfma_f32_16x16x32_bf16(ka1, qb1, s[snb], 0, 0, 0);
        }

        // softmax: lane holds 16 keys of q=qrow; 2+2 shuffles total
        float mx = -1e30f;
        #pragma unroll
        for (int snb = 0; snb < 4; ++snb) {
            const int kbase = j0 + ((snb >> 1) << 5) + (quad << 3) + ((snb & 1) << 2);
            #pragma unroll
            for (int r = 0; r < 4; ++r) {
                float v = s[snb][r] * 0.125f;             // 1/sqrt(64)
                v = (kbase + r <= qrow) ? v : -1e30f;     // causal (phys key)
                s[snb][r] = v;
                mx = fmaxf(mx, v);
            }
        }
        mx = fmaxf(mx, __shfl_xor(mx, 16));
        mx = fmaxf(mx, __shfl_xor(mx, 32));

        const float newm  = fmaxf(m_run, mx);
        const float alpha = __expf(m_run - newm);
        m_run = newm;

        float rs = 0.f;
        #pragma unroll
        for (int snb = 0; snb < 4; ++snb)
            #pragma unroll
            for (int r = 0; r < 4; ++r) {
                float pv = __expf(s[snb][r] - newm);
                s[snb][r] = pv;
                rs += pv;
            }
        rs += __shfl_xor(rs, 16);
        rs += __shfl_xor(rs, 32);
        l_run = l_run * alpha + rs;

        #pragma unroll
        for (int hs = 0; hs < 4; ++hs)
            #pragma unroll
            for (int r = 0; r < 4; ++r) o[hs][r] *= alpha;

        // P^T (registers) -> PV B-operand directly
        bf16x8 pb0, pb1;
        #pragma unroll
        for (int r = 0; r < 4; ++r) {
            pb0[r]     = (__bf16)s[0][r];
            pb0[4 + r] = (__bf16)s[1][r];
            pb1[r]     = (__bf16)s[2][r];
            pb1[4 + r] = (__bf16)s[3][r];
        }

        // O^T += Vt . P^T
        #pragma unroll
        for (int hs = 0; hs < 4; ++hs) {
            bf16x8 va0 = *(const bf16x8*)&Vlds[((hs * 2 + 0) * 64 + lane) * 8];
            bf16x8 va1 = *(const bf16x8*)&Vlds[((hs * 2 + 1) * 64 + lane) * 8];
            o[hs] = __builtin_amdgcn_mfma_f32_16x16x32_bf16(va0, pb0, o[hs], 0, 0, 0);
            o[hs] = __builtin_amdgcn_mfma_f32_16x16x32_bf16(va1, pb1, o[hs], 0, 0, 0);
        }
    }

    // epilogue: normalize and write O directly (16B stores)
    const float inv = 1.f / l_run;
    float* Ob = O + ((size_t)b * T_ + (size_t)(qt * 64 + wave * 16 + m16)) * 64;
    #pragma unroll
    for (int hs = 0; hs < 4; ++hs) {
        f32x4 v;
        #pragma unroll
        for (int r = 0; r < 4; ++r) v[r] = o[hs][r] * inv;
        *(f32x4*)(Ob + hs * 16 + quad * 4) = v;
    }
}

// ---------------------------------------------------------------------------
extern "C" void kernel_launch(void* const* d_in, const int* in_sizes, int n_in,
                              void* d_out, int out_size, void* d_ws, size_t ws_size,
                              hipStream_t stream)
{
    const float* x  = (const float*)d_in[0];
    const float* Wq = (const float*)d_in[1];
    const float* bq = (const float*)d_in[2];
    const float* Wk = (const float*)d_in[3];
    const float* bk = (const float*)d_in[4];
    const float* Wv = (const float*)d_in[5];
    const float* bv = (const float*)d_in[6];
    float* out = (float*)d_out;

    __bf16* Wp = (__bf16*)d_ws;              // 384*512 bf16         = 0.4 MB
    __bf16* Q  = Wp + 384 * 512;             // 8*2048*64 bf16       = 2 MB
    __bf16* K  = Q  + (size_t)B_ * T_ * HS_;
    __bf16* Vt = K  + (size_t)B_ * T_ * HS_; // transposed [b][h][t]

    pack_w<<<96, 256, 0, stream>>>(Wq, Wk, Wv, Wp);
    qkv_fused<<<1024, 256, 0, stream>>>(x, Wp, bq, bk, bv, Q, K, Vt);
    attn_fused<<<dim3(32, 8), 256, 0, stream>>>(Q, K, Vt, out);
}

// Round 6
// 148.120 us; speedup vs baseline: 1.1795x; 1.0679x over previous
//
#include <hip/hip_runtime.h>
#include <hip/hip_bf16.h>

typedef __bf16 bf16x8 __attribute__((ext_vector_type(8)));
typedef __bf16 bf16x4 __attribute__((ext_vector_type(4)));
typedef float  f32x4  __attribute__((ext_vector_type(4)));

#define B_  8
#define T_  2048
#define D_  1024
#define HS_ 64

// ---------------------------------------------------------------------------
// fp32 inputs/outputs; bf16 MFMA internally.
// pack_w -> qkv_fused -> attn_fused (uniform-trips blocks + LDS XOR swizzle)
//
// Round-14 post-mortem: R4's 44.5us attn = (a) 16-way LDS WRITE bank
// conflicts (c/g bits live at byte bits>=8, all == 0 mod 128 -> same bank;
// 3.78M conflict cycles) and (b) causal imbalance at exactly 1 block/CU
// (makespan = 32-tile block vs 16.5 mean).
// Fix: (a) XOR swizzle e^=((e>>7)&7)<<3 on LDS writes AND frag reads
// (bijective, verified by address spot-checks); (b) pair halftile group
// {2s,2s+1} with {126-2s,127-2s}: every block = exactly 33 tile-trips.
// Grid (32,8) x 128 thr (2 waves share staging); per-wave math unchanged.
// ---------------------------------------------------------------------------

// Kernel 0: pack the three [D,HS] fp32 weights into bf16 MFMA-fragment order.
__global__ __launch_bounds__(256) void pack_w(
    const float* __restrict__ Wq, const float* __restrict__ Wk,
    const float* __restrict__ Wv, __bf16* __restrict__ Wp)
{
    const int t    = blockIdx.x * 256 + threadIdx.x;   // 0..24575
    const int lane = t & 63;
    const int pg   = t >> 6;                           // 0..383
    const int s    = pg & 3;
    const int c    = (pg >> 2) & 31;
    const int p    = pg >> 7;
    const int m16  = lane & 15;
    const int quad = lane >> 4;

    const float* W = (p == 0) ? Wq : (p == 1) ? Wk : Wv;
    const float* src = W + (size_t)(c * 32 + quad * 8) * 64 + s * 16 + m16;
    bf16x8 frag;
    #pragma unroll
    for (int j = 0; j < 8; ++j) frag[j] = (__bf16)src[(size_t)j * 64];
    *(bf16x8*)(Wp + (size_t)pg * 512 + lane * 8) = frag;
}

// Kernel 1: fused QKV projection, K-split across waves.
__global__ __launch_bounds__(256) void qkv_fused(
    const float* __restrict__ x,     // [16384][1024] fp32
    const __bf16* __restrict__ Wp,   // [384][512] fragment-packed bf16
    const float* __restrict__ bq, const float* __restrict__ bk,
    const float* __restrict__ bv,
    __bf16* __restrict__ Q, __bf16* __restrict__ K, __bf16* __restrict__ Vt)
{
    __shared__ alignas(16) unsigned char Smem[36864];  // Xs (33792) ∪ Red (36864)

    const int rt   = blockIdx.x;                  // 0..1023
    const int wave = threadIdx.x >> 6;            // K-slice owner
    const int lane = threadIdx.x & 63;
    const int m16  = lane & 15;
    const int quad = lane >> 4;
    const int row0 = rt * 16;

    __bf16* Xs = (__bf16*)(Smem + wave * 8448);   // 16 rows x 264 (pad 8)

    // ---- Phase 1: stage x-slice (16 rows x 256 cols), fp32 -> bf16 ----
    {
        const float* xsrc = x + (size_t)row0 * 1024 + wave * 256;
        const int sr = lane >> 5;                 // 0..1
        const int sc = (lane & 31) * 8;           // 0..248
        #pragma unroll
        for (int i = 0; i < 8; ++i) {
            const int r = i * 2 + sr;
            f32x4 v0 = *(const f32x4*)(xsrc + (size_t)r * 1024 + sc);
            f32x4 v1 = *(const f32x4*)(xsrc + (size_t)r * 1024 + sc + 4);
            bf16x8 w;
            #pragma unroll
            for (int e = 0; e < 4; ++e) { w[e] = (__bf16)v0[e]; w[4 + e] = (__bf16)v1[e]; }
            *(bf16x8*)&Xs[r * 264 + sc] = w;
        }
    }
    __builtin_amdgcn_wave_barrier();   // pin DS write->read order (wave-local)

    // ---- Phase 2: K-loop with batched Wp loads ----
    f32x4 acc[3][4];
    #pragma unroll
    for (int p = 0; p < 3; ++p)
        #pragma unroll
        for (int s = 0; s < 4; ++s) acc[p][s] = {0.f, 0.f, 0.f, 0.f};

    for (int k0 = 0; k0 < 256; k0 += 32) {
        bf16x8 a = *(const bf16x8*)&Xs[m16 * 264 + k0 + quad * 8];
        const int cbase = wave * 8 + (k0 >> 5);

        bf16x8 bf[12];                 // all 12 loads in flight before any use
        #pragma unroll
        for (int ps = 0; ps < 12; ++ps) {
            const int p = ps >> 2, s = ps & 3;
            bf[ps] = *(const bf16x8*)(Wp +
                ((size_t)((p * 32 + cbase) * 4 + s) << 9) + lane * 8);
        }
        __builtin_amdgcn_sched_barrier(0);   // keep loads above, MFMAs below

        #pragma unroll
        for (int ps = 0; ps < 12; ++ps)
            acc[ps >> 2][ps & 3] =
                __builtin_amdgcn_mfma_f32_16x16x32_bf16(a, bf[ps], acc[ps >> 2][ps & 3], 0, 0, 0);
    }

    // ---- Phase 3: cross-wave reduce (Red overlays dead Xs) + epilogue ----
    f32x4* Red = (f32x4*)Smem;                    // [3][12][64]
    __syncthreads();                              // all Xs reads done
    if (wave != 0) {
        #pragma unroll
        for (int p = 0; p < 3; ++p)
            #pragma unroll
            for (int s = 0; s < 4; ++s)
                Red[((wave - 1) * 12 + p * 4 + s) * 64 + lane] = acc[p][s];
    }
    __syncthreads();
    if (wave != 0) return;

    #pragma unroll
    for (int p = 0; p < 3; ++p)
        #pragma unroll
        for (int s = 0; s < 4; ++s) {
            f32x4 sum = acc[p][s];
            #pragma unroll
            for (int w = 0; w < 3; ++w) {
                f32x4 v = Red[(w * 12 + p * 4 + s) * 64 + lane];
                #pragma unroll
                for (int e = 0; e < 4; ++e) sum[e] += v[e];
            }
            acc[p][s] = sum;
        }

    // Q epilogue (p=0)
    #pragma unroll
    for (int s = 0; s < 4; ++s) {
        const int h = s * 16 + m16;
        const float bia = bq[h];
        #pragma unroll
        for (int r = 0; r < 4; ++r)
            Q[(size_t)(row0 + quad * 4 + r) * 64 + h] = (__bf16)(acc[0][s][r] + bia);
    }
    // K epilogue (p=1)
    #pragma unroll
    for (int s = 0; s < 4; ++s) {
        const int h = s * 16 + m16;
        const float bia = bk[h];
        #pragma unroll
        for (int r = 0; r < 4; ++r)
            K[(size_t)(row0 + quad * 4 + r) * 64 + h] = (__bf16)(acc[1][s][r] + bia);
    }
    // V epilogue (p=2), transposed Vt[b][h][t]
    {
        const int bidx = row0 >> 11;
        const int t0   = (row0 & 2047) + quad * 4;
        #pragma unroll
        for (int s = 0; s < 4; ++s) {
            const int h = s * 16 + m16;
            const float bia = bv[h];
            bf16x4 pack;
            #pragma unroll
            for (int r = 0; r < 4; ++r) pack[r] = (__bf16)(acc[2][s][r] + bia);
            *(bf16x4*)(Vt + (size_t)bidx * (HS_ * T_) + (size_t)h * T_ + t0) = pack;
        }
    }
}

// Kernel 2: single-pass causal attention, uniform-work blocks.
// grid = (32, 8), block = 128 (2 waves; wave w owns halftile h0+w of 16 q
// rows). Block processes halftile group 2s then group 126-2s: trip counts
// (s/2+1) + (32-s/2) == 33 for every block -> zero causal imbalance.
// LDS staging shared by the 2 waves; XOR swizzle kills write conflicts.
__global__ __launch_bounds__(128) void attn_fused(
    const __bf16* __restrict__ Q,   // [8][2048][64]
    const __bf16* __restrict__ K,   // [8][2048][64]
    const __bf16* __restrict__ Vt,  // [8][64][2048]
    float* __restrict__ O)          // [8][2048][64] fp32
{
    __shared__ alignas(16) __bf16 Klds[4096];   // 8KB, one 64-key tile
    __shared__ alignas(16) __bf16 Vlds[4096];

    const int s  = blockIdx.x;      // 0..31 (work pair id)
    const int b  = blockIdx.y;      // batch

    const int tid  = threadIdx.x;   // 0..127
    const int wave = tid >> 6;      // 0..1
    const int lane = tid & 63;
    const int m16  = lane & 15;
    const int quad = lane >> 4;

    const __bf16* Qb = Q  + (size_t)b * T_ * HS_;
    const __bf16* Kb = K  + (size_t)b * T_ * HS_;
    const __bf16* Vb = Vt + (size_t)b * HS_ * T_;
    float* Obase     = O  + (size_t)b * T_ * HS_;

    // Staging: thread covers pieces p = i*128 + tid (i=0..3) of the 512
    // 16B pieces (K tile 8KB + V tile 8KB). trow = p>>3, tcol = p&7.
    const int tr0  = tid >> 3;      // 0..15
    const int tcol = tid & 7;
    const int c    = tcol & 3;
    const int gco  = tcol >> 2;

    // LDS element offsets (constant), with bank XOR swizzle e^=((e>>7)&7)<<3
    int kOff[4], vOff[4];
    #pragma unroll
    for (int i = 0; i < 4; ++i) {
        const int trow = tr0 + 16 * i;
        const int snb  = ((trow >> 5) << 1) | ((trow >> 2) & 1);
        const int mk   = (((trow >> 3) & 3) << 2) | (trow & 3);
        const int ek   = (((snb << 1) | gco) << 9) + c * 128 + mk * 8;
        kOff[i] = ek ^ (((ek >> 7) & 7) << 3);
        const int ev   = ((((trow >> 4) << 1) | gco) << 9) + c * 128 + (trow & 15) * 8;
        vOff[i] = ev ^ (((ev >> 7) & 7) << 3);
    }
    const __bf16* kgb[4];
    const __bf16* vgb[4];
    #pragma unroll
    for (int i = 0; i < 4; ++i) {
        const int trow = tr0 + 16 * i;
        kgb[i] = Kb + (size_t)trow * 64 + tcol * 8;   // + j0*64 per tile
        vgb[i] = Vb + (size_t)trow * T_ + tcol * 8;   // + j0    per tile
    }

    // Fragment-read offsets (same XOR applied): for group g = 2*snb+i,
    // elem = g*512 + (lane*8 ^ ((quad|(i<<2))<<3)).
    const int rsw0 = (lane * 8) ^ (quad << 3);
    const int rsw1 = (lane * 8) ^ ((quad | 4) << 3);

    auto phase = [&](const int h0) {
        const int qrow  = (h0 + wave) * 16 + m16;   // this lane's q row
        const int jtmax = h0 >> 2;                  // same for wave 0/1

        bf16x8 qb0 = *(const bf16x8*)(Qb + (size_t)qrow * 64 + quad * 8);
        bf16x8 qb1 = *(const bf16x8*)(Qb + (size_t)qrow * 64 + 32 + quad * 8);

        f32x4 o[4];                                 // O^T: h=hs*16+quad*4+r
        #pragma unroll
        for (int hs = 0; hs < 4; ++hs) o[hs] = {0.f, 0.f, 0.f, 0.f};
        float m_run = -1e30f, l_run = 0.f;

        // prologue: tile 0 staged into registers (coalesced 16B loads)
        bf16x8 kr[4], vr[4];
        #pragma unroll
        for (int i = 0; i < 4; ++i) {
            kr[i] = *(const bf16x8*)(kgb[i]);
            vr[i] = *(const bf16x8*)(vgb[i]);
        }

        for (int jt = 0; jt <= jtmax; ++jt) {
            const int j0 = jt * 64;

            __syncthreads();               // prior tile's LDS reads done
            #pragma unroll
            for (int i = 0; i < 4; ++i) {
                *(bf16x8*)&Klds[kOff[i]] = kr[i];
                *(bf16x8*)&Vlds[vOff[i]] = vr[i];
            }
            __syncthreads();               // staged tile visible

            // reg-prefetch next tile; hides under this tile's compute
            if (jt < jtmax) {
                const size_t kadd = (size_t)(j0 + 64) * 64;
                #pragma unroll
                for (int i = 0; i < 4; ++i) {
                    kr[i] = *(const bf16x8*)(kgb[i] + kadd);
                    vr[i] = *(const bf16x8*)(vgb[i] + j0 + 64);
                }
            }
            __builtin_amdgcn_sched_barrier(0);   // loads issue above compute

            // S^T = K.Q^T
            f32x4 sv[4];
            #pragma unroll
            for (int snb = 0; snb < 4; ++snb) sv[snb] = {0.f, 0.f, 0.f, 0.f};
            #pragma unroll
            for (int snb = 0; snb < 4; ++snb) {
                bf16x8 ka0 = *(const bf16x8*)&Klds[snb * 1024 + rsw0];
                bf16x8 ka1 = *(const bf16x8*)&Klds[snb * 1024 + 512 + rsw1];
                sv[snb] = __builtin_amdgcn_mfma_f32_16x16x32_bf16(ka0, qb0, sv[snb], 0, 0, 0);
                sv[snb] = __builtin_amdgcn_mfma_f32_16x16x32_bf16(ka1, qb1, sv[snb], 0, 0, 0);
            }

            // softmax: lane holds 16 keys of q=qrow; 2+2 shuffles
            float mx = -1e30f;
            #pragma unroll
            for (int snb = 0; snb < 4; ++snb) {
                const int kbase = j0 + ((snb >> 1) << 5) + (quad << 3) + ((snb & 1) << 2);
                #pragma unroll
                for (int r = 0; r < 4; ++r) {
                    float v = sv[snb][r] * 0.125f;            // 1/sqrt(64)
                    v = (kbase + r <= qrow) ? v : -1e30f;     // causal
                    sv[snb][r] = v;
                    mx = fmaxf(mx, v);
                }
            }
            mx = fmaxf(mx, __shfl_xor(mx, 16));
            mx = fmaxf(mx, __shfl_xor(mx, 32));

            const float newm  = fmaxf(m_run, mx);
            const float alpha = __expf(m_run - newm);
            m_run = newm;

            float rs = 0.f;
            #pragma unroll
            for (int snb = 0; snb < 4; ++snb)
                #pragma unroll
                for (int r = 0; r < 4; ++r) {
                    float pv = __expf(sv[snb][r] - newm);
                    sv[snb][r] = pv;
                    rs += pv;
                }
            rs += __shfl_xor(rs, 16);
            rs += __shfl_xor(rs, 32);
            l_run = l_run * alpha + rs;

            #pragma unroll
            for (int hs = 0; hs < 4; ++hs)
                #pragma unroll
                for (int r = 0; r < 4; ++r) o[hs][r] *= alpha;

            // P^T (registers) -> PV B-operand directly
            bf16x8 pb0, pb1;
            #pragma unroll
            for (int r = 0; r < 4; ++r) {
                pb0[r]     = (__bf16)sv[0][r];
                pb0[4 + r] = (__bf16)sv[1][r];
                pb1[r]     = (__bf16)sv[2][r];
                pb1[4 + r] = (__bf16)sv[3][r];
            }

            // O^T += Vt . P^T
            #pragma unroll
            for (int hs = 0; hs < 4; ++hs) {
                bf16x8 va0 = *(const bf16x8*)&Vlds[hs * 1024 + rsw0];
                bf16x8 va1 = *(const bf16x8*)&Vlds[hs * 1024 + 512 + rsw1];
                o[hs] = __builtin_amdgcn_mfma_f32_16x16x32_bf16(va0, pb0, o[hs], 0, 0, 0);
                o[hs] = __builtin_amdgcn_mfma_f32_16x16x32_bf16(va1, pb1, o[hs], 0, 0, 0);
            }
        }

        // epilogue: normalize and write this wave's 16 rows
        const float inv = 1.f / l_run;
        float* Ob = Obase + (size_t)qrow * 64;
        #pragma unroll
        for (int hs = 0; hs < 4; ++hs) {
            f32x4 v;
            #pragma unroll
            for (int r = 0; r < 4; ++r) v[r] = o[hs][r] * inv;
            *(f32x4*)(Ob + hs * 16 + quad * 4) = v;
        }
    };

    phase(2 * s);          // trips s/2 + 1
    phase(126 - 2 * s);    // trips 32 - s/2   (total 33, uniform)
}

// ---------------------------------------------------------------------------
extern "C" void kernel_launch(void* const* d_in, const int* in_sizes, int n_in,
                              void* d_out, int out_size, void* d_ws, size_t ws_size,
                              hipStream_t stream)
{
    const float* x  = (const float*)d_in[0];
    const float* Wq = (const float*)d_in[1];
    const float* bq = (const float*)d_in[2];
    const float* Wk = (const float*)d_in[3];
    const float* bk = (const float*)d_in[4];
    const float* Wv = (const float*)d_in[5];
    const float* bv = (const float*)d_in[6];
    float* out = (float*)d_out;

    __bf16* Wp = (__bf16*)d_ws;              // 384*512 bf16         = 0.4 MB
    __bf16* Q  = Wp + 384 * 512;             // 8*2048*64 bf16       = 2 MB
    __bf16* K  = Q  + (size_t)B_ * T_ * HS_;
    __bf16* Vt = K  + (size_t)B_ * T_ * HS_; // transposed [b][h][t]

    pack_w<<<96, 256, 0, stream>>>(Wq, Wk, Wv, Wp);
    qkv_fused<<<1024, 256, 0, stream>>>(x, Wp, bq, bk, bv, Q, K, Vt);
    attn_fused<<<dim3(32, 8), 128, 0, stream>>>(Q, K, Vt, out);
}

// Round 7
// 139.273 us; speedup vs baseline: 1.2544x; 1.0635x over previous
//
#include <hip/hip_runtime.h>
#include <hip/hip_bf16.h>

typedef __bf16 bf16x8 __attribute__((ext_vector_type(8)));
typedef __bf16 bf16x4 __attribute__((ext_vector_type(4)));
typedef float  f32x4  __attribute__((ext_vector_type(4)));

#define B_  8
#define T_  2048
#define D_  1024
#define HS_ 64

// ---------------------------------------------------------------------------
// fp32 in/out; bf16 MFMA internally.
// pack_w -> qkv_fused (writes Q row-major + Kp/Vp FRAGMENT-PACKED)
//        -> attn_fused (no LDS tiles: coalesced frag loads from L2,
//                       split-K across 2 waves, paired phases, in-block merge)
//
// Round-16 theory: attn was occupancy-starved (2 waves/CU) and paid LDS
// staging+barriers per trip only to PERMUTE K/V into frag order. Since we
// produce K/V, qkv now writes them frag-packed (Kp/Vp[b][tile][g][lane][8]);
// attn frag loads become coalesced 1KB/wave L2 hits. 512 blocks x 2 waves,
// block owns halftile pair (h,127-h) = 34 tiles uniform; waves split tiles
// by parity (~17 trips each); block-local LDS merge once per phase.
// Index maps producer->consumer verified by construction + spot checks:
//   key = tb*16+quad*4+r == (snb>>1)*32+(m16c>>2)*8+(snb&1)*4+(m16c&3)
//   col = s*16+m16      == i*32 + quadc*8 + j
// ---------------------------------------------------------------------------

// Kernel 0: pack the three [D,HS] fp32 weights into bf16 MFMA-fragment order.
__global__ __launch_bounds__(256) void pack_w(
    const float* __restrict__ Wq, const float* __restrict__ Wk,
    const float* __restrict__ Wv, __bf16* __restrict__ Wp)
{
    const int t    = blockIdx.x * 256 + threadIdx.x;   // 0..24575
    const int lane = t & 63;
    const int pg   = t >> 6;                           // 0..383
    const int s    = pg & 3;
    const int c    = (pg >> 2) & 31;
    const int p    = pg >> 7;
    const int m16  = lane & 15;
    const int quad = lane >> 4;

    const float* W = (p == 0) ? Wq : (p == 1) ? Wk : Wv;
    const float* src = W + (size_t)(c * 32 + quad * 8) * 64 + s * 16 + m16;
    bf16x8 frag;
    #pragma unroll
    for (int j = 0; j < 8; ++j) frag[j] = (__bf16)src[(size_t)j * 64];
    *(bf16x8*)(Wp + (size_t)pg * 512 + lane * 8) = frag;
}

// Kernel 1: fused QKV projection, K-split across waves.
// Epilogue now writes K and V in attn fragment order (Kp/Vp).
__global__ __launch_bounds__(256) void qkv_fused(
    const float* __restrict__ x,     // [16384][1024] fp32
    const __bf16* __restrict__ Wp,   // [384][512] fragment-packed bf16
    const float* __restrict__ bq, const float* __restrict__ bk,
    const float* __restrict__ bv,
    __bf16* __restrict__ Q,          // [8][2048][64] row-major
    __bf16* __restrict__ Kp,         // [8][32][8][64][8] frag-packed
    __bf16* __restrict__ Vp)         // [8][32][8][64][8] frag-packed
{
    __shared__ alignas(16) unsigned char Smem[36864];  // Xs (33792) ∪ Red (36864)

    const int rt   = blockIdx.x;                  // 0..1023
    const int wave = threadIdx.x >> 6;            // K-slice owner
    const int lane = threadIdx.x & 63;
    const int m16  = lane & 15;
    const int quad = lane >> 4;
    const int row0 = rt * 16;

    __bf16* Xs = (__bf16*)(Smem + wave * 8448);   // 16 rows x 264 (pad 8)

    // ---- Phase 1: stage x-slice (16 rows x 256 cols), fp32 -> bf16 ----
    {
        const float* xsrc = x + (size_t)row0 * 1024 + wave * 256;
        const int sr = lane >> 5;                 // 0..1
        const int sc = (lane & 31) * 8;           // 0..248
        #pragma unroll
        for (int i = 0; i < 8; ++i) {
            const int r = i * 2 + sr;
            f32x4 v0 = *(const f32x4*)(xsrc + (size_t)r * 1024 + sc);
            f32x4 v1 = *(const f32x4*)(xsrc + (size_t)r * 1024 + sc + 4);
            bf16x8 w;
            #pragma unroll
            for (int e = 0; e < 4; ++e) { w[e] = (__bf16)v0[e]; w[4 + e] = (__bf16)v1[e]; }
            *(bf16x8*)&Xs[r * 264 + sc] = w;
        }
    }
    __builtin_amdgcn_wave_barrier();   // pin DS write->read order (wave-local)

    // ---- Phase 2: K-loop with batched Wp loads ----
    f32x4 acc[3][4];
    #pragma unroll
    for (int p = 0; p < 3; ++p)
        #pragma unroll
        for (int s = 0; s < 4; ++s) acc[p][s] = {0.f, 0.f, 0.f, 0.f};

    for (int k0 = 0; k0 < 256; k0 += 32) {
        bf16x8 a = *(const bf16x8*)&Xs[m16 * 264 + k0 + quad * 8];
        const int cbase = wave * 8 + (k0 >> 5);

        bf16x8 bf[12];                 // all 12 loads in flight before any use
        #pragma unroll
        for (int ps = 0; ps < 12; ++ps) {
            const int p = ps >> 2, s = ps & 3;
            bf[ps] = *(const bf16x8*)(Wp +
                ((size_t)((p * 32 + cbase) * 4 + s) << 9) + lane * 8);
        }
        __builtin_amdgcn_sched_barrier(0);   // keep loads above, MFMAs below

        #pragma unroll
        for (int ps = 0; ps < 12; ++ps)
            acc[ps >> 2][ps & 3] =
                __builtin_amdgcn_mfma_f32_16x16x32_bf16(a, bf[ps], acc[ps >> 2][ps & 3], 0, 0, 0);
    }

    // ---- Phase 3: cross-wave reduce (Red overlays dead Xs) + epilogue ----
    f32x4* Red = (f32x4*)Smem;                    // [3][12][64]
    __syncthreads();                              // all Xs reads done
    if (wave != 0) {
        #pragma unroll
        for (int p = 0; p < 3; ++p)
            #pragma unroll
            for (int s = 0; s < 4; ++s)
                Red[((wave - 1) * 12 + p * 4 + s) * 64 + lane] = acc[p][s];
    }
    __syncthreads();
    if (wave != 0) return;

    #pragma unroll
    for (int p = 0; p < 3; ++p)
        #pragma unroll
        for (int s = 0; s < 4; ++s) {
            f32x4 sum = acc[p][s];
            #pragma unroll
            for (int w = 0; w < 3; ++w) {
                f32x4 v = Red[(w * 12 + p * 4 + s) * 64 + lane];
                #pragma unroll
                for (int e = 0; e < 4; ++e) sum[e] += v[e];
            }
            acc[p][s] = sum;
        }

    // Q epilogue (p=0): row-major (attn loads 2 frags per phase, cost ~0)
    #pragma unroll
    for (int s = 0; s < 4; ++s) {
        const int h = s * 16 + m16;
        const float bia = bq[h];
        #pragma unroll
        for (int r = 0; r < 4; ++r)
            Q[(size_t)(row0 + quad * 4 + r) * 64 + h] = (__bf16)(acc[0][s][r] + bia);
    }

    const int tb = (row0 >> 4) & 3;               // 16-row quarter within tile
    const int jt = (row0 >> 6) & 31;              // key tile
    const int bb = row0 >> 11;                    // batch
    __bf16* kpt = Kp + (((size_t)bb * 32 + jt) * 8) * 512;
    __bf16* vpt = Vp + (((size_t)bb * 32 + jt) * 8) * 512;

    // K epilogue (p=1): scatter into frag-packed Kp
    {
        const int snb  = ((tb >> 1) << 1) | (quad & 1);
        const int m16b = ((tb & 1) << 3) | ((quad >> 1) << 2);  // + r
        #pragma unroll
        for (int s = 0; s < 4; ++s) {
            const int h = s * 16 + m16;
            const float bia = bk[h];
            const int g     = snb * 2 + (s >> 1);
            const int quadc = ((s & 1) << 1) | (m16 >> 3);
            const int j     = m16 & 7;
            #pragma unroll
            for (int r = 0; r < 4; ++r)
                kpt[(size_t)g * 512 + (quadc * 16 + m16b + r) * 8 + j] =
                    (__bf16)(acc[1][s][r] + bia);
        }
    }
    // V epilogue (p=2): frag-packed Vp, r-contiguous -> bf16x4 stores
    {
        const int lanec = ((((tb & 1) << 1) | (quad >> 1)) << 4) + m16;
        const int jbase = (quad & 1) << 2;
        #pragma unroll
        for (int s = 0; s < 4; ++s) {
            const int h = s * 16 + m16;
            const float bia = bv[h];
            const int g = s * 2 + (tb >> 1);
            bf16x4 pack;
            #pragma unroll
            for (int r = 0; r < 4; ++r) pack[r] = (__bf16)(acc[2][s][r] + bia);
            *(bf16x4*)(vpt + (size_t)g * 512 + lanec * 8 + jbase) = pack;
        }
    }
}

// Kernel 2: causal attention, no LDS tiles.
// grid (64,8) x 128 thr. Block p owns halftiles hA=p, hB=127-p (34 tiles
// total, uniform). Waves split each phase's tiles by parity (~17 trips).
// Per trip: 16 coalesced frag loads (ping-pong prefetch) + 16 MFMA + lean
// softmax (scale folded into exp2 fma; mask only on diagonal tile).
// Block-local LDS merge of the 2 split-K partials per phase.
__global__ __launch_bounds__(128) void attn_fused(
    const __bf16* __restrict__ Q,    // [8][2048][64]
    const __bf16* __restrict__ Kp,   // [8][32][8][64][8]
    const __bf16* __restrict__ Vp,   // [8][32][8][64][8]
    float* __restrict__ O)           // [8][2048][64] fp32
{
    __shared__ float Mrg[64][20];    // wave1 partial: o[16], m, l

    const int p  = blockIdx.x;       // pair id 0..63
    const int b  = blockIdx.y;       // batch
    const int wave = threadIdx.x >> 6;
    const int lane = threadIdx.x & 63;
    const int m16  = lane & 15;
    const int quad = lane >> 4;
    const float SC = 0.18033688f;    // 0.125 * log2(e)

    const __bf16* Qb = Q  + (size_t)b * T_ * HS_;
    const __bf16* Kb = Kp + (size_t)b * 32 * 4096;
    const __bf16* Vb = Vp + (size_t)b * 32 * 4096;
    float* Obase     = O  + (size_t)b * T_ * HS_;

#define LOADT(KA, VA, JT)                                                  \
    {                                                                      \
        const __bf16* kb_ = Kb + (size_t)(JT) * 4096 + lane * 8;           \
        const __bf16* vb_ = Vb + (size_t)(JT) * 4096 + lane * 8;           \
        _Pragma("unroll")                                                  \
        for (int g_ = 0; g_ < 8; ++g_) {                                   \
            KA[g_] = *(const bf16x8*)(kb_ + g_ * 512);                     \
            VA[g_] = *(const bf16x8*)(vb_ + g_ * 512);                     \
        }                                                                  \
    }

#define STEP(CK, CV, NK, NV)                                               \
    {                                                                      \
        const int j0 = jt * 64;                                            \
        f32x4 sv[4];                                                       \
        _Pragma("unroll")                                                  \
        for (int sn_ = 0; sn_ < 4; ++sn_) {                                \
            sv[sn_] = {0.f, 0.f, 0.f, 0.f};                                \
            sv[sn_] = __builtin_amdgcn_mfma_f32_16x16x32_bf16(CK[sn_*2],   qb0, sv[sn_], 0, 0, 0); \
            sv[sn_] = __builtin_amdgcn_mfma_f32_16x16x32_bf16(CK[sn_*2+1], qb1, sv[sn_], 0, 0, 0); \
        }                                                                  \
        if (jt + 2 < ntiles) LOADT(NK, NV, jt + 2);                        \
        __builtin_amdgcn_sched_barrier(0);                                 \
        if (jt == ntiles - 1) {   /* diagonal tile: causal mask */         \
            _Pragma("unroll")                                              \
            for (int sn_ = 0; sn_ < 4; ++sn_) {                            \
                const int kbase = j0 + ((sn_ >> 1) << 5) + (quad << 3) + ((sn_ & 1) << 2); \
                _Pragma("unroll")                                          \
                for (int r_ = 0; r_ < 4; ++r_)                             \
                    sv[sn_][r_] = (kbase + r_ <= qrow) ? sv[sn_][r_] : -3e38f; \
            }                                                              \
        }                                                                  \
        float mx = -3e38f;                                                 \
        _Pragma("unroll")                                                  \
        for (int sn_ = 0; sn_ < 4; ++sn_)                                  \
            _Pragma("unroll")                                              \
            for (int r_ = 0; r_ < 4; ++r_) mx = fmaxf(mx, sv[sn_][r_]);    \
        mx = fmaxf(mx, __shfl_xor(mx, 16));                                \
        mx = fmaxf(mx, __shfl_xor(mx, 32));                                \
        const float newm  = fmaxf(m_run, mx);                              \
        const float alpha = exp2f((m_run - newm) * SC);                    \
        m_run = newm;                                                      \
        const float nm = newm * SC;                                        \
        float rs = 0.f;                                                    \
        _Pragma("unroll")                                                  \
        for (int sn_ = 0; sn_ < 4; ++sn_)                                  \
            _Pragma("unroll")                                              \
            for (int r_ = 0; r_ < 4; ++r_) {                               \
                float pv_ = exp2f(__builtin_fmaf(sv[sn_][r_], SC, -nm));   \
                sv[sn_][r_] = pv_;                                         \
                rs += pv_;                                                 \
            }                                                              \
        rs += __shfl_xor(rs, 16);                                          \
        rs += __shfl_xor(rs, 32);                                          \
        l_run = l_run * alpha + rs;                                        \
        _Pragma("unroll")                                                  \
        for (int hs_ = 0; hs_ < 4; ++hs_)                                  \
            _Pragma("unroll")                                              \
            for (int r_ = 0; r_ < 4; ++r_) o[hs_][r_] *= alpha;            \
        bf16x8 pb0, pb1;                                                   \
        _Pragma("unroll")                                                  \
        for (int r_ = 0; r_ < 4; ++r_) {                                   \
            pb0[r_]     = (__bf16)sv[0][r_];                               \
            pb0[4 + r_] = (__bf16)sv[1][r_];                               \
            pb1[r_]     = (__bf16)sv[2][r_];                               \
            pb1[4 + r_] = (__bf16)sv[3][r_];                               \
        }                                                                  \
        _Pragma("unroll")                                                  \
        for (int hs_ = 0; hs_ < 4; ++hs_) {                                \
            o[hs_] = __builtin_amdgcn_mfma_f32_16x16x32_bf16(CV[hs_*2],   pb0, o[hs_], 0, 0, 0); \
            o[hs_] = __builtin_amdgcn_mfma_f32_16x16x32_bf16(CV[hs_*2+1], pb1, o[hs_], 0, 0, 0); \
        }                                                                  \
    }

    auto runPhase = [&](const int h) {
        const int ntiles = (h >> 2) + 1;
        const int qrow   = h * 16 + m16;

        bf16x8 qb0 = *(const bf16x8*)(Qb + (size_t)qrow * 64 + quad * 8);
        bf16x8 qb1 = *(const bf16x8*)(Qb + (size_t)qrow * 64 + 32 + quad * 8);

        f32x4 o[4];
        #pragma unroll
        for (int hs = 0; hs < 4; ++hs) o[hs] = {0.f, 0.f, 0.f, 0.f};
        float m_run = -3e38f, l_run = 0.f;

        bf16x8 kA[8], vA[8], kB[8], vB[8];
        int jt = wave;                     // split-K by tile parity
        if (jt < ntiles) {
            LOADT(kA, vA, jt);
            while (true) {
                STEP(kA, vA, kB, vB);
                jt += 2; if (jt >= ntiles) break;
                STEP(kB, vB, kA, vA);
                jt += 2; if (jt >= ntiles) break;
            }
        }

        // block-local split-K merge (wave1 publishes, wave0 combines+writes)
        if (wave == 1) {
            #pragma unroll
            for (int hs = 0; hs < 4; ++hs)
                #pragma unroll
                for (int r = 0; r < 4; ++r) Mrg[lane][hs * 4 + r] = o[hs][r];
            Mrg[lane][16] = m_run;
            Mrg[lane][17] = l_run;
        }
        __syncthreads();
        if (wave == 0) {
            const float m1 = Mrg[lane][16];
            const float l1 = Mrg[lane][17];
            const float M  = fmaxf(m_run, m1);
            const float a0 = exp2f((m_run - M) * SC);
            const float a1 = exp2f((m1 - M) * SC);
            const float inv = 1.f / (l_run * a0 + l1 * a1);
            float* Ob = Obase + (size_t)qrow * 64;
            #pragma unroll
            for (int hs = 0; hs < 4; ++hs) {
                f32x4 v;
                #pragma unroll
                for (int r = 0; r < 4; ++r)
                    v[r] = (o[hs][r] * a0 + Mrg[lane][hs * 4 + r] * a1) * inv;
                *(f32x4*)(Ob + hs * 16 + quad * 4) = v;
            }
        }
        __syncthreads();   // Mrg reusable for next phase
    };

    runPhase(p);           // (p>>2)+1 tiles
    runPhase(127 - p);     // 32-(p>>2) tiles  -> 34 uniform per block
#undef STEP
#undef LOADT
}

// ---------------------------------------------------------------------------
extern "C" void kernel_launch(void* const* d_in, const int* in_sizes, int n_in,
                              void* d_out, int out_size, void* d_ws, size_t ws_size,
                              hipStream_t stream)
{
    const float* x  = (const float*)d_in[0];
    const float* Wq = (const float*)d_in[1];
    const float* bq = (const float*)d_in[2];
    const float* Wk = (const float*)d_in[3];
    const float* bk = (const float*)d_in[4];
    const float* Wv = (const float*)d_in[5];
    const float* bv = (const float*)d_in[6];
    float* out = (float*)d_out;

    __bf16* Wp = (__bf16*)d_ws;              // 384*512 bf16         = 0.4 MB
    __bf16* Q  = Wp + 384 * 512;             // 8*2048*64 bf16       = 2 MB
    __bf16* Kp = Q  + (size_t)B_ * T_ * HS_; // frag-packed          = 2 MB
    __bf16* Vp = Kp + (size_t)B_ * T_ * HS_; // frag-packed          = 2 MB

    pack_w<<<96, 256, 0, stream>>>(Wq, Wk, Wv, Wp);
    qkv_fused<<<1024, 256, 0, stream>>>(x, Wp, bq, bk, bv, Q, Kp, Vp);
    attn_fused<<<dim3(64, 8), 128, 0, stream>>>(Q, Kp, Vp, out);
}

// Round 8
// 132.542 us; speedup vs baseline: 1.3181x; 1.0508x over previous
//
#include <hip/hip_runtime.h>
#include <hip/hip_bf16.h>

typedef __bf16 bf16x8 __attribute__((ext_vector_type(8)));
typedef __bf16 bf16x4 __attribute__((ext_vector_type(4)));
typedef float  f32x4  __attribute__((ext_vector_type(4)));

#define B_  8
#define T_  2048
#define D_  1024
#define HS_ 64

// ---------------------------------------------------------------------------
// fp32 in/out; bf16 MFMA internally.
// pack_w -> qkv_fused (writes Q row-major + Kp/Vp FRAGMENT-PACKED)
//        -> attn_fused (no LDS tiles; 4-wave split-K, paired phases)
//
// Round-17 theory: R7's attn (~25us) was occupancy-bound: 1024 waves =
// 1 wave/SIMD, all L2 latency + serial softmax chain exposed. Same work,
// 4 waves/block splitting tiles by parity -> 8 waves/CU (2/SIMD), per-wave
// trips 34 -> ~8.5. Block-local 4-way merge (15KB LDS). qkv unchanged.
// ---------------------------------------------------------------------------

// Kernel 0: pack the three [D,HS] fp32 weights into bf16 MFMA-fragment order.
__global__ __launch_bounds__(256) void pack_w(
    const float* __restrict__ Wq, const float* __restrict__ Wk,
    const float* __restrict__ Wv, __bf16* __restrict__ Wp)
{
    const int t    = blockIdx.x * 256 + threadIdx.x;   // 0..24575
    const int lane = t & 63;
    const int pg   = t >> 6;                           // 0..383
    const int s    = pg & 3;
    const int c    = (pg >> 2) & 31;
    const int p    = pg >> 7;
    const int m16  = lane & 15;
    const int quad = lane >> 4;

    const float* W = (p == 0) ? Wq : (p == 1) ? Wk : Wv;
    const float* src = W + (size_t)(c * 32 + quad * 8) * 64 + s * 16 + m16;
    bf16x8 frag;
    #pragma unroll
    for (int j = 0; j < 8; ++j) frag[j] = (__bf16)src[(size_t)j * 64];
    *(bf16x8*)(Wp + (size_t)pg * 512 + lane * 8) = frag;
}

// Kernel 1: fused QKV projection, K-split across waves.
// Epilogue writes K and V in attn fragment order (Kp/Vp).
__global__ __launch_bounds__(256) void qkv_fused(
    const float* __restrict__ x,     // [16384][1024] fp32
    const __bf16* __restrict__ Wp,   // [384][512] fragment-packed bf16
    const float* __restrict__ bq, const float* __restrict__ bk,
    const float* __restrict__ bv,
    __bf16* __restrict__ Q,          // [8][2048][64] row-major
    __bf16* __restrict__ Kp,         // [8][32][8][64][8] frag-packed
    __bf16* __restrict__ Vp)         // [8][32][8][64][8] frag-packed
{
    __shared__ alignas(16) unsigned char Smem[36864];  // Xs (33792) ∪ Red (36864)

    const int rt   = blockIdx.x;                  // 0..1023
    const int wave = threadIdx.x >> 6;            // K-slice owner
    const int lane = threadIdx.x & 63;
    const int m16  = lane & 15;
    const int quad = lane >> 4;
    const int row0 = rt * 16;

    __bf16* Xs = (__bf16*)(Smem + wave * 8448);   // 16 rows x 264 (pad 8)

    // ---- Phase 1: stage x-slice (16 rows x 256 cols), fp32 -> bf16 ----
    {
        const float* xsrc = x + (size_t)row0 * 1024 + wave * 256;
        const int sr = lane >> 5;                 // 0..1
        const int sc = (lane & 31) * 8;           // 0..248
        #pragma unroll
        for (int i = 0; i < 8; ++i) {
            const int r = i * 2 + sr;
            f32x4 v0 = *(const f32x4*)(xsrc + (size_t)r * 1024 + sc);
            f32x4 v1 = *(const f32x4*)(xsrc + (size_t)r * 1024 + sc + 4);
            bf16x8 w;
            #pragma unroll
            for (int e = 0; e < 4; ++e) { w[e] = (__bf16)v0[e]; w[4 + e] = (__bf16)v1[e]; }
            *(bf16x8*)&Xs[r * 264 + sc] = w;
        }
    }
    __builtin_amdgcn_wave_barrier();   // pin DS write->read order (wave-local)

    // ---- Phase 2: K-loop with batched Wp loads ----
    f32x4 acc[3][4];
    #pragma unroll
    for (int p = 0; p < 3; ++p)
        #pragma unroll
        for (int s = 0; s < 4; ++s) acc[p][s] = {0.f, 0.f, 0.f, 0.f};

    for (int k0 = 0; k0 < 256; k0 += 32) {
        bf16x8 a = *(const bf16x8*)&Xs[m16 * 264 + k0 + quad * 8];
        const int cbase = wave * 8 + (k0 >> 5);

        bf16x8 bf[12];                 // all 12 loads in flight before any use
        #pragma unroll
        for (int ps = 0; ps < 12; ++ps) {
            const int p = ps >> 2, s = ps & 3;
            bf[ps] = *(const bf16x8*)(Wp +
                ((size_t)((p * 32 + cbase) * 4 + s) << 9) + lane * 8);
        }
        __builtin_amdgcn_sched_barrier(0);   // keep loads above, MFMAs below

        #pragma unroll
        for (int ps = 0; ps < 12; ++ps)
            acc[ps >> 2][ps & 3] =
                __builtin_amdgcn_mfma_f32_16x16x32_bf16(a, bf[ps], acc[ps >> 2][ps & 3], 0, 0, 0);
    }

    // ---- Phase 3: cross-wave reduce (Red overlays dead Xs) + epilogue ----
    f32x4* Red = (f32x4*)Smem;                    // [3][12][64]
    __syncthreads();                              // all Xs reads done
    if (wave != 0) {
        #pragma unroll
        for (int p = 0; p < 3; ++p)
            #pragma unroll
            for (int s = 0; s < 4; ++s)
                Red[((wave - 1) * 12 + p * 4 + s) * 64 + lane] = acc[p][s];
    }
    __syncthreads();
    if (wave != 0) return;

    #pragma unroll
    for (int p = 0; p < 3; ++p)
        #pragma unroll
        for (int s = 0; s < 4; ++s) {
            f32x4 sum = acc[p][s];
            #pragma unroll
            for (int w = 0; w < 3; ++w) {
                f32x4 v = Red[(w * 12 + p * 4 + s) * 64 + lane];
                #pragma unroll
                for (int e = 0; e < 4; ++e) sum[e] += v[e];
            }
            acc[p][s] = sum;
        }

    // Q epilogue (p=0): row-major
    #pragma unroll
    for (int s = 0; s < 4; ++s) {
        const int h = s * 16 + m16;
        const float bia = bq[h];
        #pragma unroll
        for (int r = 0; r < 4; ++r)
            Q[(size_t)(row0 + quad * 4 + r) * 64 + h] = (__bf16)(acc[0][s][r] + bia);
    }

    const int tb = (row0 >> 4) & 3;               // 16-row quarter within tile
    const int jt = (row0 >> 6) & 31;              // key tile
    const int bb = row0 >> 11;                    // batch
    __bf16* kpt = Kp + (((size_t)bb * 32 + jt) * 8) * 512;
    __bf16* vpt = Vp + (((size_t)bb * 32 + jt) * 8) * 512;

    // K epilogue (p=1): scatter into frag-packed Kp
    {
        const int snb  = ((tb >> 1) << 1) | (quad & 1);
        const int m16b = ((tb & 1) << 3) | ((quad >> 1) << 2);  // + r
        #pragma unroll
        for (int s = 0; s < 4; ++s) {
            const int h = s * 16 + m16;
            const float bia = bk[h];
            const int g     = snb * 2 + (s >> 1);
            const int quadc = ((s & 1) << 1) | (m16 >> 3);
            const int j     = m16 & 7;
            #pragma unroll
            for (int r = 0; r < 4; ++r)
                kpt[(size_t)g * 512 + (quadc * 16 + m16b + r) * 8 + j] =
                    (__bf16)(acc[1][s][r] + bia);
        }
    }
    // V epilogue (p=2): frag-packed Vp, r-contiguous -> bf16x4 stores
    {
        const int lanec = ((((tb & 1) << 1) | (quad >> 1)) << 4) + m16;
        const int jbase = (quad & 1) << 2;
        #pragma unroll
        for (int s = 0; s < 4; ++s) {
            const int h = s * 16 + m16;
            const float bia = bv[h];
            const int g = s * 2 + (tb >> 1);
            bf16x4 pack;
            #pragma unroll
            for (int r = 0; r < 4; ++r) pack[r] = (__bf16)(acc[2][s][r] + bia);
            *(bf16x4*)(vpt + (size_t)g * 512 + lanec * 8 + jbase) = pack;
        }
    }
}

// Kernel 2: causal attention, no LDS tiles, 4-wave split-K.
// grid (64,8) x 256 thr. Block p owns halftiles hA=p, hB=127-p (34 tiles
// uniform). The 4 waves split each phase's tiles by parity (jt=wave, +=4):
// ~8.5 trips/wave, 8 waves/CU. Per trip: 16 coalesced frag loads (ping-pong
// prefetch) + 16 MFMA + lean softmax. Block-local 4-way LDS merge per phase.
__global__ __launch_bounds__(256) void attn_fused(
    const __bf16* __restrict__ Q,    // [8][2048][64]
    const __bf16* __restrict__ Kp,   // [8][32][8][64][8]
    const __bf16* __restrict__ Vp,   // [8][32][8][64][8]
    float* __restrict__ O)           // [8][2048][64] fp32
{
    __shared__ float Mrg[3][64][20];  // waves 1-3 partials: o[16], m, l

    const int p  = blockIdx.x;       // pair id 0..63
    const int b  = blockIdx.y;       // batch
    const int wave = threadIdx.x >> 6;   // 0..3 (split-K slice)
    const int lane = threadIdx.x & 63;
    const int m16  = lane & 15;
    const int quad = lane >> 4;
    const float SC = 0.18033688f;    // 0.125 * log2(e)

    const __bf16* Qb = Q  + (size_t)b * T_ * HS_;
    const __bf16* Kb = Kp + (size_t)b * 32 * 4096;
    const __bf16* Vb = Vp + (size_t)b * 32 * 4096;
    float* Obase     = O  + (size_t)b * T_ * HS_;

#define LOADT(KA, VA, JT)                                                  \
    {                                                                      \
        const __bf16* kb_ = Kb + (size_t)(JT) * 4096 + lane * 8;           \
        const __bf16* vb_ = Vb + (size_t)(JT) * 4096 + lane * 8;           \
        _Pragma("unroll")                                                  \
        for (int g_ = 0; g_ < 8; ++g_) {                                   \
            KA[g_] = *(const bf16x8*)(kb_ + g_ * 512);                     \
            VA[g_] = *(const bf16x8*)(vb_ + g_ * 512);                     \
        }                                                                  \
    }

#define STEP(CK, CV, NK, NV)                                               \
    {                                                                      \
        const int j0 = jt * 64;                                            \
        f32x4 sv[4];                                                       \
        _Pragma("unroll")                                                  \
        for (int sn_ = 0; sn_ < 4; ++sn_) {                                \
            sv[sn_] = {0.f, 0.f, 0.f, 0.f};                                \
            sv[sn_] = __builtin_amdgcn_mfma_f32_16x16x32_bf16(CK[sn_*2],   qb0, sv[sn_], 0, 0, 0); \
            sv[sn_] = __builtin_amdgcn_mfma_f32_16x16x32_bf16(CK[sn_*2+1], qb1, sv[sn_], 0, 0, 0); \
        }                                                                  \
        if (jt + 4 < ntiles) LOADT(NK, NV, jt + 4);                        \
        __builtin_amdgcn_sched_barrier(0);                                 \
        if (jt == ntiles - 1) {   /* diagonal tile: causal mask */         \
            _Pragma("unroll")                                              \
            for (int sn_ = 0; sn_ < 4; ++sn_) {                            \
                const int kbase = j0 + ((sn_ >> 1) << 5) + (quad << 3) + ((sn_ & 1) << 2); \
                _Pragma("unroll")                                          \
                for (int r_ = 0; r_ < 4; ++r_)                             \
                    sv[sn_][r_] = (kbase + r_ <= qrow) ? sv[sn_][r_] : -3e38f; \
            }                                                              \
        }                                                                  \
        float mx = -3e38f;                                                 \
        _Pragma("unroll")                                                  \
        for (int sn_ = 0; sn_ < 4; ++sn_)                                  \
            _Pragma("unroll")                                              \
            for (int r_ = 0; r_ < 4; ++r_) mx = fmaxf(mx, sv[sn_][r_]);    \
        mx = fmaxf(mx, __shfl_xor(mx, 16));                                \
        mx = fmaxf(mx, __shfl_xor(mx, 32));                                \
        const float newm  = fmaxf(m_run, mx);                              \
        const float alpha = exp2f((m_run - newm) * SC);                    \
        m_run = newm;                                                      \
        const float nm = newm * SC;                                        \
        float rs = 0.f;                                                    \
        _Pragma("unroll")                                                  \
        for (int sn_ = 0; sn_ < 4; ++sn_)                                  \
            _Pragma("unroll")                                              \
            for (int r_ = 0; r_ < 4; ++r_) {                               \
                float pv_ = exp2f(__builtin_fmaf(sv[sn_][r_], SC, -nm));   \
                sv[sn_][r_] = pv_;                                         \
                rs += pv_;                                                 \
            }                                                              \
        rs += __shfl_xor(rs, 16);                                          \
        rs += __shfl_xor(rs, 32);                                          \
        l_run = l_run * alpha + rs;                                        \
        _Pragma("unroll")                                                  \
        for (int hs_ = 0; hs_ < 4; ++hs_)                                  \
            _Pragma("unroll")                                              \
            for (int r_ = 0; r_ < 4; ++r_) o[hs_][r_] *= alpha;            \
        bf16x8 pb0, pb1;                                                   \
        _Pragma("unroll")                                                  \
        for (int r_ = 0; r_ < 4; ++r_) {                                   \
            pb0[r_]     = (__bf16)sv[0][r_];                               \
            pb0[4 + r_] = (__bf16)sv[1][r_];                               \
            pb1[r_]     = (__bf16)sv[2][r_];                               \
            pb1[4 + r_] = (__bf16)sv[3][r_];                               \
        }                                                                  \
        _Pragma("unroll")                                                  \
        for (int hs_ = 0; hs_ < 4; ++hs_) {                                \
            o[hs_] = __builtin_amdgcn_mfma_f32_16x16x32_bf16(CV[hs_*2],   pb0, o[hs_], 0, 0, 0); \
            o[hs_] = __builtin_amdgcn_mfma_f32_16x16x32_bf16(CV[hs_*2+1], pb1, o[hs_], 0, 0, 0); \
        }                                                                  \
    }

    auto runPhase = [&](const int h) {
        const int ntiles = (h >> 2) + 1;
        const int qrow   = h * 16 + m16;

        bf16x8 qb0 = *(const bf16x8*)(Qb + (size_t)qrow * 64 + quad * 8);
        bf16x8 qb1 = *(const bf16x8*)(Qb + (size_t)qrow * 64 + 32 + quad * 8);

        f32x4 o[4];
        #pragma unroll
        for (int hs = 0; hs < 4; ++hs) o[hs] = {0.f, 0.f, 0.f, 0.f};
        float m_run = -3e38f, l_run = 0.f;

        bf16x8 kA[8], vA[8], kB[8], vB[8];
        int jt = wave;                     // 4-way split-K by tile parity
        if (jt < ntiles) {
            LOADT(kA, vA, jt);
            while (true) {
                STEP(kA, vA, kB, vB);
                jt += 4; if (jt >= ntiles) break;
                STEP(kB, vB, kA, vA);
                jt += 4; if (jt >= ntiles) break;
            }
        }

        // block-local 4-way split-K merge (waves 1-3 publish, wave0 writes)
        if (wave != 0) {
            #pragma unroll
            for (int hs = 0; hs < 4; ++hs)
                #pragma unroll
                for (int r = 0; r < 4; ++r) Mrg[wave - 1][lane][hs * 4 + r] = o[hs][r];
            Mrg[wave - 1][lane][16] = m_run;
            Mrg[wave - 1][lane][17] = l_run;
        }
        __syncthreads();
        if (wave == 0) {
            float mw[3], lw[3];
            #pragma unroll
            for (int w = 0; w < 3; ++w) {
                mw[w] = Mrg[w][lane][16];
                lw[w] = Mrg[w][lane][17];
            }
            float M = fmaxf(fmaxf(m_run, mw[0]), fmaxf(mw[1], mw[2]));
            const float a0 = exp2f((m_run - M) * SC);
            float aw[3];
            float den = l_run * a0;
            #pragma unroll
            for (int w = 0; w < 3; ++w) {
                aw[w] = exp2f((mw[w] - M) * SC);
                den += lw[w] * aw[w];
            }
            const float inv = 1.f / den;
            float* Ob = Obase + (size_t)qrow * 64;
            #pragma unroll
            for (int hs = 0; hs < 4; ++hs) {
                f32x4 v;
                #pragma unroll
                for (int r = 0; r < 4; ++r) {
                    float acc = o[hs][r] * a0;
                    #pragma unroll
                    for (int w = 0; w < 3; ++w)
                        acc += Mrg[w][lane][hs * 4 + r] * aw[w];
                    v[r] = acc * inv;
                }
                *(f32x4*)(Ob + hs * 16 + quad * 4) = v;
            }
        }
        __syncthreads();   // Mrg reusable for next phase
    };

    runPhase(p);           // (p>>2)+1 tiles
    runPhase(127 - p);     // 32-(p>>2) tiles  -> 34 uniform per block
#undef STEP
#undef LOADT
}

// ---------------------------------------------------------------------------
extern "C" void kernel_launch(void* const* d_in, const int* in_sizes, int n_in,
                              void* d_out, int out_size, void* d_ws, size_t ws_size,
                              hipStream_t stream)
{
    const float* x  = (const float*)d_in[0];
    const float* Wq = (const float*)d_in[1];
    const float* bq = (const float*)d_in[2];
    const float* Wk = (const float*)d_in[3];
    const float* bk = (const float*)d_in[4];
    const float* Wv = (const float*)d_in[5];
    const float* bv = (const float*)d_in[6];
    float* out = (float*)d_out;

    __bf16* Wp = (__bf16*)d_ws;              // 384*512 bf16         = 0.4 MB
    __bf16* Q  = Wp + 384 * 512;             // 8*2048*64 bf16       = 2 MB
    __bf16* Kp = Q  + (size_t)B_ * T_ * HS_; // frag-packed          = 2 MB
    __bf16* Vp = Kp + (size_t)B_ * T_ * HS_; // frag-packed          = 2 MB

    pack_w<<<96, 256, 0, stream>>>(Wq, Wk, Wv, Wp);
    qkv_fused<<<1024, 256, 0, stream>>>(x, Wp, bq, bk, bv, Q, Kp, Vp);
    attn_fused<<<dim3(64, 8), 256, 0, stream>>>(Q, Kp, Vp, out);
}

// Round 9
// 130.944 us; speedup vs baseline: 1.3342x; 1.0122x over previous
//
#include <hip/hip_runtime.h>
#include <hip/hip_bf16.h>

typedef __bf16 bf16x8 __attribute__((ext_vector_type(8)));
typedef __bf16 bf16x4 __attribute__((ext_vector_type(4)));
typedef float  f32x4  __attribute__((ext_vector_type(4)));

#define B_  8
#define T_  2048
#define D_  1024
#define HS_ 64

// ---------------------------------------------------------------------------
// fp32 in/out; bf16 MFMA internally.
// pack_w -> qkv_fused (M=32/wave: half the Wp L2 traffic, 2x MFMA density)
//        -> attn_fused (no LDS tiles; 4-wave split-K, paired phases)
//
// Round-18 theory: attn is ~19us; the 113.7us constant hides qkv. qkv M=16
// is L2-BW-bound: 12KB Wp per 60cy of MFMA (~219cy/kstep at 56 B/cy/CU L2),
// 393 MB chip-wide Wp traffic. M=32/wave halves Wp traffic (196 MB) and
// doubles MFMA per load (24 MFMA / 12 loads). Grid 512, LDS 73.7KB
// (Xs 67.6 ∪ Red 73.7), 2 blocks/CU. attn/pack_w byte-identical (attribution).
// ---------------------------------------------------------------------------

// Kernel 0: pack the three [D,HS] fp32 weights into bf16 MFMA-fragment order.
__global__ __launch_bounds__(256) void pack_w(
    const float* __restrict__ Wq, const float* __restrict__ Wk,
    const float* __restrict__ Wv, __bf16* __restrict__ Wp)
{
    const int t    = blockIdx.x * 256 + threadIdx.x;   // 0..24575
    const int lane = t & 63;
    const int pg   = t >> 6;                           // 0..383
    const int s    = pg & 3;
    const int c    = (pg >> 2) & 31;
    const int p    = pg >> 7;
    const int m16  = lane & 15;
    const int quad = lane >> 4;

    const float* W = (p == 0) ? Wq : (p == 1) ? Wk : Wv;
    const float* src = W + (size_t)(c * 32 + quad * 8) * 64 + s * 16 + m16;
    bf16x8 frag;
    #pragma unroll
    for (int j = 0; j < 8; ++j) frag[j] = (__bf16)src[(size_t)j * 64];
    *(bf16x8*)(Wp + (size_t)pg * 512 + lane * 8) = frag;
}

// Kernel 1: fused QKV projection, K-split across waves, M=32 rows/wave.
// grid = 512 blocks (32 rows each), block = 256 = 4 waves.
// Per kstep: 2 ds_read A-frags, 12 Wp fragments batched into registers,
// sched_barrier, then 24 MFMAs (2 row-halves x 12).
__global__ __launch_bounds__(256) void qkv_fused(
    const float* __restrict__ x,     // [16384][1024] fp32
    const __bf16* __restrict__ Wp,   // [384][512] fragment-packed bf16
    const float* __restrict__ bq, const float* __restrict__ bk,
    const float* __restrict__ bv,
    __bf16* __restrict__ Q,          // [8][2048][64] row-major
    __bf16* __restrict__ Kp,         // [8][32][8][64][8] frag-packed
    __bf16* __restrict__ Vp)         // [8][32][8][64][8] frag-packed
{
    __shared__ alignas(16) unsigned char Smem[73728];  // Xs(67584) ∪ Red(73728)

    const int rt   = blockIdx.x;                  // 0..511
    const int wave = threadIdx.x >> 6;            // K-slice owner
    const int lane = threadIdx.x & 63;
    const int m16  = lane & 15;
    const int quad = lane >> 4;
    const int row0 = rt * 32;

    __bf16* Xs = (__bf16*)(Smem + wave * 16896);  // 32 rows x 264 (pad 8)

    // ---- Phase 1: stage x-slice (32 rows x 256 cols), fp32 -> bf16 ----
    {
        const float* xsrc = x + (size_t)row0 * 1024 + wave * 256;
        const int sr = lane >> 5;                 // 0..1
        const int sc = (lane & 31) * 8;           // 0..248
        #pragma unroll
        for (int i = 0; i < 16; ++i) {
            const int r = i * 2 + sr;
            f32x4 v0 = *(const f32x4*)(xsrc + (size_t)r * 1024 + sc);
            f32x4 v1 = *(const f32x4*)(xsrc + (size_t)r * 1024 + sc + 4);
            bf16x8 w;
            #pragma unroll
            for (int e = 0; e < 4; ++e) { w[e] = (__bf16)v0[e]; w[4 + e] = (__bf16)v1[e]; }
            *(bf16x8*)&Xs[r * 264 + sc] = w;
        }
    }
    __builtin_amdgcn_wave_barrier();   // pin DS write->read order (wave-local)

    // ---- Phase 2: K-loop, batched Wp loads, 2 row-halves ----
    f32x4 acc[3][4][2];
    #pragma unroll
    for (int p = 0; p < 3; ++p)
        #pragma unroll
        for (int s = 0; s < 4; ++s)
            #pragma unroll
            for (int t = 0; t < 2; ++t) acc[p][s][t] = {0.f, 0.f, 0.f, 0.f};

    for (int k0 = 0; k0 < 256; k0 += 32) {
        bf16x8 a0 = *(const bf16x8*)&Xs[m16 * 264 + k0 + quad * 8];
        bf16x8 a1 = *(const bf16x8*)&Xs[(16 + m16) * 264 + k0 + quad * 8];
        const int cbase = wave * 8 + (k0 >> 5);

        bf16x8 bf[12];                 // all 12 loads in flight before any use
        #pragma unroll
        for (int ps = 0; ps < 12; ++ps) {
            const int p = ps >> 2, s = ps & 3;
            bf[ps] = *(const bf16x8*)(Wp +
                ((size_t)((p * 32 + cbase) * 4 + s) << 9) + lane * 8);
        }
        __builtin_amdgcn_sched_barrier(0);   // keep loads above, MFMAs below

        #pragma unroll
        for (int ps = 0; ps < 12; ++ps) {
            acc[ps >> 2][ps & 3][0] =
                __builtin_amdgcn_mfma_f32_16x16x32_bf16(a0, bf[ps], acc[ps >> 2][ps & 3][0], 0, 0, 0);
            acc[ps >> 2][ps & 3][1] =
                __builtin_amdgcn_mfma_f32_16x16x32_bf16(a1, bf[ps], acc[ps >> 2][ps & 3][1], 0, 0, 0);
        }
    }

    // ---- Phase 3: cross-wave reduce (Red overlays dead Xs) + epilogue ----
    f32x4* Red = (f32x4*)Smem;                    // [3][24][64]
    __syncthreads();                              // all Xs reads done
    if (wave != 0) {
        #pragma unroll
        for (int p = 0; p < 3; ++p)
            #pragma unroll
            for (int s = 0; s < 4; ++s)
                #pragma unroll
                for (int t = 0; t < 2; ++t)
                    Red[((wave - 1) * 24 + (p * 4 + s) * 2 + t) * 64 + lane] = acc[p][s][t];
    }
    __syncthreads();
    if (wave != 0) return;

    #pragma unroll
    for (int p = 0; p < 3; ++p)
        #pragma unroll
        for (int s = 0; s < 4; ++s)
            #pragma unroll
            for (int t = 0; t < 2; ++t) {
                f32x4 sum = acc[p][s][t];
                #pragma unroll
                for (int w = 0; w < 3; ++w) {
                    f32x4 v = Red[(w * 24 + (p * 4 + s) * 2 + t) * 64 + lane];
                    #pragma unroll
                    for (int e = 0; e < 4; ++e) sum[e] += v[e];
                }
                acc[p][s][t] = sum;
            }

    #pragma unroll
    for (int t = 0; t < 2; ++t) {
        const int row0t = row0 + t * 16;

        // Q epilogue (p=0): row-major
        #pragma unroll
        for (int s = 0; s < 4; ++s) {
            const int h = s * 16 + m16;
            const float bia = bq[h];
            #pragma unroll
            for (int r = 0; r < 4; ++r)
                Q[(size_t)(row0t + quad * 4 + r) * 64 + h] = (__bf16)(acc[0][s][t][r] + bia);
        }

        const int tb = (row0t >> 4) & 3;              // 16-row quarter in tile
        const int jt = (row0t >> 6) & 31;             // key tile
        const int bb = row0t >> 11;                   // batch
        __bf16* kpt = Kp + (((size_t)bb * 32 + jt) * 8) * 512;
        __bf16* vpt = Vp + (((size_t)bb * 32 + jt) * 8) * 512;

        // K epilogue (p=1): scatter into frag-packed Kp
        {
            const int snb  = ((tb >> 1) << 1) | (quad & 1);
            const int m16b = ((tb & 1) << 3) | ((quad >> 1) << 2);  // + r
            #pragma unroll
            for (int s = 0; s < 4; ++s) {
                const int h = s * 16 + m16;
                const float bia = bk[h];
                const int g     = snb * 2 + (s >> 1);
                const int quadc = ((s & 1) << 1) | (m16 >> 3);
                const int j     = m16 & 7;
                #pragma unroll
                for (int r = 0; r < 4; ++r)
                    kpt[(size_t)g * 512 + (quadc * 16 + m16b + r) * 8 + j] =
                        (__bf16)(acc[1][s][t][r] + bia);
            }
        }
        // V epilogue (p=2): frag-packed Vp, r-contiguous -> bf16x4 stores
        {
            const int lanec = ((((tb & 1) << 1) | (quad >> 1)) << 4) + m16;
            const int jbase = (quad & 1) << 2;
            #pragma unroll
            for (int s = 0; s < 4; ++s) {
                const int h = s * 16 + m16;
                const float bia = bv[h];
                const int g = s * 2 + (tb >> 1);
                bf16x4 pack;
                #pragma unroll
                for (int r = 0; r < 4; ++r) pack[r] = (__bf16)(acc[2][s][t][r] + bia);
                *(bf16x4*)(vpt + (size_t)g * 512 + lanec * 8 + jbase) = pack;
            }
        }
    }
}

// Kernel 2: causal attention, no LDS tiles, 4-wave split-K.
// grid (64,8) x 256 thr. Block p owns halftiles hA=p, hB=127-p (34 tiles
// uniform). The 4 waves split each phase's tiles by parity (jt=wave, +=4):
// ~8.5 trips/wave, 8 waves/CU. Per trip: 16 coalesced frag loads (ping-pong
// prefetch) + 16 MFMA + lean softmax. Block-local 4-way LDS merge per phase.
__global__ __launch_bounds__(256) void attn_fused(
    const __bf16* __restrict__ Q,    // [8][2048][64]
    const __bf16* __restrict__ Kp,   // [8][32][8][64][8]
    const __bf16* __restrict__ Vp,   // [8][32][8][64][8]
    float* __restrict__ O)           // [8][2048][64] fp32
{
    __shared__ float Mrg[3][64][20];  // waves 1-3 partials: o[16], m, l

    const int p  = blockIdx.x;       // pair id 0..63
    const int b  = blockIdx.y;       // batch
    const int wave = threadIdx.x >> 6;   // 0..3 (split-K slice)
    const int lane = threadIdx.x & 63;
    const int m16  = lane & 15;
    const int quad = lane >> 4;
    const float SC = 0.18033688f;    // 0.125 * log2(e)

    const __bf16* Qb = Q  + (size_t)b * T_ * HS_;
    const __bf16* Kb = Kp + (size_t)b * 32 * 4096;
    const __bf16* Vb = Vp + (size_t)b * 32 * 4096;
    float* Obase     = O  + (size_t)b * T_ * HS_;

#define LOADT(KA, VA, JT)                                                  \
    {                                                                      \
        const __bf16* kb_ = Kb + (size_t)(JT) * 4096 + lane * 8;           \
        const __bf16* vb_ = Vb + (size_t)(JT) * 4096 + lane * 8;           \
        _Pragma("unroll")                                                  \
        for (int g_ = 0; g_ < 8; ++g_) {                                   \
            KA[g_] = *(const bf16x8*)(kb_ + g_ * 512);                     \
            VA[g_] = *(const bf16x8*)(vb_ + g_ * 512);                     \
        }                                                                  \
    }

#define STEP(CK, CV, NK, NV)                                               \
    {                                                                      \
        const int j0 = jt * 64;                                            \
        f32x4 sv[4];                                                       \
        _Pragma("unroll")                                                  \
        for (int sn_ = 0; sn_ < 4; ++sn_) {                                \
            sv[sn_] = {0.f, 0.f, 0.f, 0.f};                                \
            sv[sn_] = __builtin_amdgcn_mfma_f32_16x16x32_bf16(CK[sn_*2],   qb0, sv[sn_], 0, 0, 0); \
            sv[sn_] = __builtin_amdgcn_mfma_f32_16x16x32_bf16(CK[sn_*2+1], qb1, sv[sn_], 0, 0, 0); \
        }                                                                  \
        if (jt + 4 < ntiles) LOADT(NK, NV, jt + 4);                        \
        __builtin_amdgcn_sched_barrier(0);                                 \
        if (jt == ntiles - 1) {   /* diagonal tile: causal mask */         \
            _Pragma("unroll")                                              \
            for (int sn_ = 0; sn_ < 4; ++sn_) {                            \
                const int kbase = j0 + ((sn_ >> 1) << 5) + (quad << 3) + ((sn_ & 1) << 2); \
                _Pragma("unroll")                                          \
                for (int r_ = 0; r_ < 4; ++r_)                             \
                    sv[sn_][r_] = (kbase + r_ <= qrow) ? sv[sn_][r_] : -3e38f; \
            }                                                              \
        }                                                                  \
        float mx = -3e38f;                                                 \
        _Pragma("unroll")                                                  \
        for (int sn_ = 0; sn_ < 4; ++sn_)                                  \
            _Pragma("unroll")                                              \
            for (int r_ = 0; r_ < 4; ++r_) mx = fmaxf(mx, sv[sn_][r_]);    \
        mx = fmaxf(mx, __shfl_xor(mx, 16));                                \
        mx = fmaxf(mx, __shfl_xor(mx, 32));                                \
        const float newm  = fmaxf(m_run, mx);                              \
        const float alpha = exp2f((m_run - newm) * SC);                    \
        m_run = newm;                                                      \
        const float nm = newm * SC;                                        \
        float rs = 0.f;                                                    \
        _Pragma("unroll")                                                  \
        for (int sn_ = 0; sn_ < 4; ++sn_)                                  \
            _Pragma("unroll")                                              \
            for (int r_ = 0; r_ < 4; ++r_) {                               \
                float pv_ = exp2f(__builtin_fmaf(sv[sn_][r_], SC, -nm));   \
                sv[sn_][r_] = pv_;                                         \
                rs += pv_;                                                 \
            }                                                              \
        rs += __shfl_xor(rs, 16);                                          \
        rs += __shfl_xor(rs, 32);                                          \
        l_run = l_run * alpha + rs;                                        \
        _Pragma("unroll")                                                  \
        for (int hs_ = 0; hs_ < 4; ++hs_)                                  \
            _Pragma("unroll")                                              \
            for (int r_ = 0; r_ < 4; ++r_) o[hs_][r_] *= alpha;            \
        bf16x8 pb0, pb1;                                                   \
        _Pragma("unroll")                                                  \
        for (int r_ = 0; r_ < 4; ++r_) {                                   \
            pb0[r_]     = (__bf16)sv[0][r_];                               \
            pb0[4 + r_] = (__bf16)sv[1][r_];                               \
            pb1[r_]     = (__bf16)sv[2][r_];                               \
            pb1[4 + r_] = (__bf16)sv[3][r_];                               \
        }                                                                  \
        _Pragma("unroll")                                                  \
        for (int hs_ = 0; hs_ < 4; ++hs_) {                                \
            o[hs_] = __builtin_amdgcn_mfma_f32_16x16x32_bf16(CV[hs_*2],   pb0, o[hs_], 0, 0, 0); \
            o[hs_] = __builtin_amdgcn_mfma_f32_16x16x32_bf16(CV[hs_*2+1], pb1, o[hs_], 0, 0, 0); \
        }                                                                  \
    }

    auto runPhase = [&](const int h) {
        const int ntiles = (h >> 2) + 1;
        const int qrow   = h * 16 + m16;

        bf16x8 qb0 = *(const bf16x8*)(Qb + (size_t)qrow * 64 + quad * 8);
        bf16x8 qb1 = *(const bf16x8*)(Qb + (size_t)qrow * 64 + 32 + quad * 8);

        f32x4 o[4];
        #pragma unroll
        for (int hs = 0; hs < 4; ++hs) o[hs] = {0.f, 0.f, 0.f, 0.f};
        float m_run = -3e38f, l_run = 0.f;

        bf16x8 kA[8], vA[8], kB[8], vB[8];
        int jt = wave;                     // 4-way split-K by tile parity
        if (jt < ntiles) {
            LOADT(kA, vA, jt);
            while (true) {
                STEP(kA, vA, kB, vB);
                jt += 4; if (jt >= ntiles) break;
                STEP(kB, vB, kA, vA);
                jt += 4; if (jt >= ntiles) break;
            }
        }

        // block-local 4-way split-K merge (waves 1-3 publish, wave0 writes)
        if (wave != 0) {
            #pragma unroll
            for (int hs = 0; hs < 4; ++hs)
                #pragma unroll
                for (int r = 0; r < 4; ++r) Mrg[wave - 1][lane][hs * 4 + r] = o[hs][r];
            Mrg[wave - 1][lane][16] = m_run;
            Mrg[wave - 1][lane][17] = l_run;
        }
        __syncthreads();
        if (wave == 0) {
            float mw[3], lw[3];
            #pragma unroll
            for (int w = 0; w < 3; ++w) {
                mw[w] = Mrg[w][lane][16];
                lw[w] = Mrg[w][lane][17];
            }
            float M = fmaxf(fmaxf(m_run, mw[0]), fmaxf(mw[1], mw[2]));
            const float a0 = exp2f((m_run - M) * SC);
            float aw[3];
            float den = l_run * a0;
            #pragma unroll
            for (int w = 0; w < 3; ++w) {
                aw[w] = exp2f((mw[w] - M) * SC);
                den += lw[w] * aw[w];
            }
            const float inv = 1.f / den;
            float* Ob = Obase + (size_t)qrow * 64;
            #pragma unroll
            for (int hs = 0; hs < 4; ++hs) {
                f32x4 v;
                #pragma unroll
                for (int r = 0; r < 4; ++r) {
                    float acc = o[hs][r] * a0;
                    #pragma unroll
                    for (int w = 0; w < 3; ++w)
                        acc += Mrg[w][lane][hs * 4 + r] * aw[w];
                    v[r] = acc * inv;
                }
                *(f32x4*)(Ob + hs * 16 + quad * 4) = v;
            }
        }
        __syncthreads();   // Mrg reusable for next phase
    };

    runPhase(p);           // (p>>2)+1 tiles
    runPhase(127 - p);     // 32-(p>>2) tiles  -> 34 uniform per block
#undef STEP
#undef LOADT
}

// ---------------------------------------------------------------------------
extern "C" void kernel_launch(void* const* d_in, const int* in_sizes, int n_in,
                              void* d_out, int out_size, void* d_ws, size_t ws_size,
                              hipStream_t stream)
{
    const float* x  = (const float*)d_in[0];
    const float* Wq = (const float*)d_in[1];
    const float* bq = (const float*)d_in[2];
    const float* Wk = (const float*)d_in[3];
    const float* bk = (const float*)d_in[4];
    const float* Wv = (const float*)d_in[5];
    const float* bv = (const float*)d_in[6];
    float* out = (float*)d_out;

    __bf16* Wp = (__bf16*)d_ws;              // 384*512 bf16         = 0.4 MB
    __bf16* Q  = Wp + 384 * 512;             // 8*2048*64 bf16       = 2 MB
    __bf16* Kp = Q  + (size_t)B_ * T_ * HS_; // frag-packed          = 2 MB
    __bf16* Vp = Kp + (size_t)B_ * T_ * HS_; // frag-packed          = 2 MB

    pack_w<<<96, 256, 0, stream>>>(Wq, Wk, Wv, Wp);
    qkv_fused<<<512, 256, 0, stream>>>(x, Wp, bq, bk, bv, Q, Kp, Vp);
    attn_fused<<<dim3(64, 8), 256, 0, stream>>>(Q, Kp, Vp, out);
}

// Round 10
// 128.051 us; speedup vs baseline: 1.3643x; 1.0226x over previous
//
#include <hip/hip_runtime.h>
#include <hip/hip_bf16.h>

typedef __bf16 bf16x8 __attribute__((ext_vector_type(8)));
typedef __bf16 bf16x4 __attribute__((ext_vector_type(4)));
typedef float  f32x4  __attribute__((ext_vector_type(4)));

#define B_  8
#define T_  2048
#define D_  1024
#define HS_ 64

// ---------------------------------------------------------------------------
// fp32 in/out; bf16 MFMA internally.
// pack_w -> qkv_fused (M=32/wave + CROSS-KSTEP ping-pong Wp prefetch)
//        -> attn_fused (fulltile: 32 q rows/wave, 2x MFMA per loaded frag;
//                       8-wave split-K, paired fulltiles, 8-way LDS merge)
//
// Round-19 post-mortem: R9 (half Wp traffic) was neutral -> qkv is
// SERIALIZATION-bound: sched_barrier per kstep blocks cross-iteration
// pipelining (issue->wait->mfma ~500cy serial). Budget: fills 84 + pack 2
// + qkv 19 + attn 19 + gaps 6.
// This round: (1) qkv ping-pong bfA/bfB across ksteps (counted waits,
// TLP covers residual); (2) attn fulltile — both halves of fulltile f
// need IDENTICAL tile range ((2f)>>2==(2f+1)>>2), so each K/V frag load
// feeds 2x MFMA; chip L2 traffic halves (256 blocks x same per-block).
// ---------------------------------------------------------------------------

// Kernel 0: pack the three [D,HS] fp32 weights into bf16 MFMA-fragment order.
__global__ __launch_bounds__(256) void pack_w(
    const float* __restrict__ Wq, const float* __restrict__ Wk,
    const float* __restrict__ Wv, __bf16* __restrict__ Wp)
{
    const int t    = blockIdx.x * 256 + threadIdx.x;   // 0..24575
    const int lane = t & 63;
    const int pg   = t >> 6;                           // 0..383
    const int s    = pg & 3;
    const int c    = (pg >> 2) & 31;
    const int p    = pg >> 7;
    const int m16  = lane & 15;
    const int quad = lane >> 4;

    const float* W = (p == 0) ? Wq : (p == 1) ? Wk : Wv;
    const float* src = W + (size_t)(c * 32 + quad * 8) * 64 + s * 16 + m16;
    bf16x8 frag;
    #pragma unroll
    for (int j = 0; j < 8; ++j) frag[j] = (__bf16)src[(size_t)j * 64];
    *(bf16x8*)(Wp + (size_t)pg * 512 + lane * 8) = frag;
}

// Kernel 1: fused QKV projection, K-split across waves, M=32 rows/wave,
// cross-kstep ping-pong prefetch of the 12 Wp fragments.
__global__ __launch_bounds__(256) void qkv_fused(
    const float* __restrict__ x,     // [16384][1024] fp32
    const __bf16* __restrict__ Wp,   // [384][512] fragment-packed bf16
    const float* __restrict__ bq, const float* __restrict__ bk,
    const float* __restrict__ bv,
    __bf16* __restrict__ Q,          // [8][2048][64] row-major
    __bf16* __restrict__ Kp,         // [8][32][8][64][8] frag-packed
    __bf16* __restrict__ Vp)         // [8][32][8][64][8] frag-packed
{
    __shared__ alignas(16) unsigned char Smem[73728];  // Xs(67584) ∪ Red(73728)

    const int rt   = blockIdx.x;                  // 0..511
    const int wave = threadIdx.x >> 6;            // K-slice owner
    const int lane = threadIdx.x & 63;
    const int m16  = lane & 15;
    const int quad = lane >> 4;
    const int row0 = rt * 32;

    __bf16* Xs = (__bf16*)(Smem + wave * 16896);  // 32 rows x 264 (pad 8)

    // ---- Phase 1: stage x-slice (32 rows x 256 cols), fp32 -> bf16 ----
    {
        const float* xsrc = x + (size_t)row0 * 1024 + wave * 256;
        const int sr = lane >> 5;                 // 0..1
        const int sc = (lane & 31) * 8;           // 0..248
        #pragma unroll
        for (int i = 0; i < 16; ++i) {
            const int r = i * 2 + sr;
            f32x4 v0 = *(const f32x4*)(xsrc + (size_t)r * 1024 + sc);
            f32x4 v1 = *(const f32x4*)(xsrc + (size_t)r * 1024 + sc + 4);
            bf16x8 w;
            #pragma unroll
            for (int e = 0; e < 4; ++e) { w[e] = (__bf16)v0[e]; w[4 + e] = (__bf16)v1[e]; }
            *(bf16x8*)&Xs[r * 264 + sc] = w;
        }
    }
    __builtin_amdgcn_wave_barrier();   // pin DS write->read order (wave-local)

    // ---- Phase 2: K-loop, ping-pong Wp prefetch, 2 row-halves ----
    f32x4 acc[3][4][2];
    #pragma unroll
    for (int p = 0; p < 3; ++p)
        #pragma unroll
        for (int s = 0; s < 4; ++s)
            #pragma unroll
            for (int t = 0; t < 2; ++t) acc[p][s][t] = {0.f, 0.f, 0.f, 0.f};

    bf16x8 bfA[12], bfB[12];

#define WLOAD(BUF, K0)                                                     \
    {                                                                      \
        const int cb_ = wave * 8 + ((K0) >> 5);                            \
        _Pragma("unroll")                                                  \
        for (int ps_ = 0; ps_ < 12; ++ps_) {                               \
            const int p_ = ps_ >> 2, s_ = ps_ & 3;                         \
            BUF[ps_] = *(const bf16x8*)(Wp +                               \
                ((size_t)((p_ * 32 + cb_) * 4 + s_) << 9) + lane * 8);     \
        }                                                                  \
    }
#define KSTEP(BUF, K0)                                                     \
    {                                                                      \
        bf16x8 a0 = *(const bf16x8*)&Xs[m16 * 264 + (K0) + quad * 8];      \
        bf16x8 a1 = *(const bf16x8*)&Xs[(16 + m16) * 264 + (K0) + quad * 8]; \
        __builtin_amdgcn_sched_barrier(0);                                 \
        _Pragma("unroll")                                                  \
        for (int ps_ = 0; ps_ < 12; ++ps_) {                               \
            acc[ps_ >> 2][ps_ & 3][0] =                                    \
                __builtin_amdgcn_mfma_f32_16x16x32_bf16(a0, BUF[ps_], acc[ps_ >> 2][ps_ & 3][0], 0, 0, 0); \
            acc[ps_ >> 2][ps_ & 3][1] =                                    \
                __builtin_amdgcn_mfma_f32_16x16x32_bf16(a1, BUF[ps_], acc[ps_ >> 2][ps_ & 3][1], 0, 0, 0); \
        }                                                                  \
    }

    WLOAD(bfA, 0);                       // prologue
    #pragma unroll
    for (int k0 = 0; k0 < 256; k0 += 64) {
        WLOAD(bfB, k0 + 32);             // prefetch next while computing cur
        KSTEP(bfA, k0);
        if (k0 + 64 < 256) WLOAD(bfA, k0 + 64);
        KSTEP(bfB, k0 + 32);
    }
#undef KSTEP
#undef WLOAD

    // ---- Phase 3: cross-wave reduce (Red overlays dead Xs) + epilogue ----
    f32x4* Red = (f32x4*)Smem;                    // [3][24][64]
    __syncthreads();                              // all Xs reads done
    if (wave != 0) {
        #pragma unroll
        for (int p = 0; p < 3; ++p)
            #pragma unroll
            for (int s = 0; s < 4; ++s)
                #pragma unroll
                for (int t = 0; t < 2; ++t)
                    Red[((wave - 1) * 24 + (p * 4 + s) * 2 + t) * 64 + lane] = acc[p][s][t];
    }
    __syncthreads();
    if (wave != 0) return;

    #pragma unroll
    for (int p = 0; p < 3; ++p)
        #pragma unroll
        for (int s = 0; s < 4; ++s)
            #pragma unroll
            for (int t = 0; t < 2; ++t) {
                f32x4 sum = acc[p][s][t];
                #pragma unroll
                for (int w = 0; w < 3; ++w) {
                    f32x4 v = Red[(w * 24 + (p * 4 + s) * 2 + t) * 64 + lane];
                    #pragma unroll
                    for (int e = 0; e < 4; ++e) sum[e] += v[e];
                }
                acc[p][s][t] = sum;
            }

    #pragma unroll
    for (int t = 0; t < 2; ++t) {
        const int row0t = row0 + t * 16;

        // Q epilogue (p=0): row-major
        #pragma unroll
        for (int s = 0; s < 4; ++s) {
            const int h = s * 16 + m16;
            const float bia = bq[h];
            #pragma unroll
            for (int r = 0; r < 4; ++r)
                Q[(size_t)(row0t + quad * 4 + r) * 64 + h] = (__bf16)(acc[0][s][t][r] + bia);
        }

        const int tb = (row0t >> 4) & 3;              // 16-row quarter in tile
        const int jt = (row0t >> 6) & 31;             // key tile
        const int bb = row0t >> 11;                   // batch
        __bf16* kpt = Kp + (((size_t)bb * 32 + jt) * 8) * 512;
        __bf16* vpt = Vp + (((size_t)bb * 32 + jt) * 8) * 512;

        // K epilogue (p=1): scatter into frag-packed Kp
        {
            const int snb  = ((tb >> 1) << 1) | (quad & 1);
            const int m16b = ((tb & 1) << 3) | ((quad >> 1) << 2);  // + r
            #pragma unroll
            for (int s = 0; s < 4; ++s) {
                const int h = s * 16 + m16;
                const float bia = bk[h];
                const int g     = snb * 2 + (s >> 1);
                const int quadc = ((s & 1) << 1) | (m16 >> 3);
                const int j     = m16 & 7;
                #pragma unroll
                for (int r = 0; r < 4; ++r)
                    kpt[(size_t)g * 512 + (quadc * 16 + m16b + r) * 8 + j] =
                        (__bf16)(acc[1][s][t][r] + bia);
            }
        }
        // V epilogue (p=2): frag-packed Vp, r-contiguous -> bf16x4 stores
        {
            const int lanec = ((((tb & 1) << 1) | (quad >> 1)) << 4) + m16;
            const int jbase = (quad & 1) << 2;
            #pragma unroll
            for (int s = 0; s < 4; ++s) {
                const int h = s * 16 + m16;
                const float bia = bv[h];
                const int g = s * 2 + (tb >> 1);
                bf16x4 pack;
                #pragma unroll
                for (int r = 0; r < 4; ++r) pack[r] = (__bf16)(acc[2][s][t][r] + bia);
                *(bf16x4*)(vpt + (size_t)g * 512 + lanec * 8 + jbase) = pack;
            }
        }
    }
}

// Kernel 2: causal attention, fulltile scheme.
// grid (32,8) x 512 thr (8 waves). Block s owns fulltiles fA=s, fB=63-s
// (32 q rows each; both 16-row halves of a fulltile need the SAME tile
// range, ntiles=(f>>1)+1; ntA+ntB=33..34 uniform). Waves split tiles 8-way
// (jt=wave, +=8). Per trip: 16 frag loads serve 32 MFMAs (2 halves).
// K ping-ponged, V single-buffered (hides under QK+softmax).
// 8-way all-publish LDS merge per phase (waves 0/1 combine halves A/B).
__global__ __launch_bounds__(512) void attn_fused(
    const __bf16* __restrict__ Q,    // [8][2048][64]
    const __bf16* __restrict__ Kp,   // [8][32][8][64][8]
    const __bf16* __restrict__ Vp,   // [8][32][8][64][8]
    float* __restrict__ O)           // [8][2048][64] fp32
{
    __shared__ float Mrg[8][64][37];  // o_A[16], mA, lA, o_B[16], mB, lB (+pad)

    const int s  = blockIdx.x;       // fulltile pair id 0..31
    const int b  = blockIdx.y;       // batch
    const int wave = threadIdx.x >> 6;   // 0..7 (split-K slice)
    const int lane = threadIdx.x & 63;
    const int m16  = lane & 15;
    const int quad = lane >> 4;
    const float SC = 0.18033688f;    // 0.125 * log2(e)

    const __bf16* Qb = Q  + (size_t)b * T_ * HS_;
    const __bf16* Kb = Kp + (size_t)b * 32 * 4096;
    const __bf16* Vb = Vp + (size_t)b * 32 * 4096;
    float* Obase     = O  + (size_t)b * T_ * HS_;

    bf16x8 vA[8];

#define LOADK(KA, JT)                                                      \
    {                                                                      \
        const __bf16* kb_ = Kb + (size_t)(JT) * 4096 + lane * 8;           \
        _Pragma("unroll")                                                  \
        for (int g_ = 0; g_ < 8; ++g_) KA[g_] = *(const bf16x8*)(kb_ + g_ * 512); \
    }
#define LOADV(JT)                                                          \
    {                                                                      \
        const __bf16* vb_ = Vb + (size_t)(JT) * 4096 + lane * 8;           \
        _Pragma("unroll")                                                  \
        for (int g_ = 0; g_ < 8; ++g_) vA[g_] = *(const bf16x8*)(vb_ + g_ * 512); \
    }

#define STEP(CK, NK)                                                       \
    {                                                                      \
        const int j0 = jt * 64;                                            \
        LOADV(jt);                      /* V current, used after softmax */ \
        f32x4 svA[4], svB[4];                                              \
        _Pragma("unroll")                                                  \
        for (int sn_ = 0; sn_ < 4; ++sn_) {                                \
            svA[sn_] = {0.f, 0.f, 0.f, 0.f};                               \
            svB[sn_] = {0.f, 0.f, 0.f, 0.f};                               \
            svA[sn_] = __builtin_amdgcn_mfma_f32_16x16x32_bf16(CK[sn_*2],   qA0, svA[sn_], 0, 0, 0); \
            svA[sn_] = __builtin_amdgcn_mfma_f32_16x16x32_bf16(CK[sn_*2+1], qA1, svA[sn_], 0, 0, 0); \
            svB[sn_] = __builtin_amdgcn_mfma_f32_16x16x32_bf16(CK[sn_*2],   qB0, svB[sn_], 0, 0, 0); \
            svB[sn_] = __builtin_amdgcn_mfma_f32_16x16x32_bf16(CK[sn_*2+1], qB1, svB[sn_], 0, 0, 0); \
        }                                                                  \
        if (jt + 8 < ntiles) LOADK(NK, jt + 8);                            \
        __builtin_amdgcn_sched_barrier(0);                                 \
        if (jt == ntiles - 1) {   /* diagonal tile: causal mask, per half */ \
            _Pragma("unroll")                                              \
            for (int sn_ = 0; sn_ < 4; ++sn_) {                            \
                const int kbase = j0 + ((sn_ >> 1) << 5) + (quad << 3) + ((sn_ & 1) << 2); \
                _Pragma("unroll")                                          \
                for (int r_ = 0; r_ < 4; ++r_) {                           \
                    svA[sn_][r_] = (kbase + r_ <= qrowA) ? svA[sn_][r_] : -3e38f; \
                    svB[sn_][r_] = (kbase + r_ <= qrowB) ? svB[sn_][r_] : -3e38f; \
                }                                                          \
            }                                                              \
        }                                                                  \
        float mxA = -3e38f, mxB = -3e38f;                                  \
        _Pragma("unroll")                                                  \
        for (int sn_ = 0; sn_ < 4; ++sn_)                                  \
            _Pragma("unroll")                                              \
            for (int r_ = 0; r_ < 4; ++r_) {                               \
                mxA = fmaxf(mxA, svA[sn_][r_]);                            \
                mxB = fmaxf(mxB, svB[sn_][r_]);                            \
            }                                                              \
        mxA = fmaxf(mxA, __shfl_xor(mxA, 16));                             \
        mxA = fmaxf(mxA, __shfl_xor(mxA, 32));                             \
        mxB = fmaxf(mxB, __shfl_xor(mxB, 16));                             \
        mxB = fmaxf(mxB, __shfl_xor(mxB, 32));                             \
        const float newmA = fmaxf(mA, mxA);                                \
        const float newmB = fmaxf(mB, mxB);                                \
        const float alA = exp2f((mA - newmA) * SC);                        \
        const float alB = exp2f((mB - newmB) * SC);                        \
        mA = newmA; mB = newmB;                                            \
        const float nmA = newmA * SC, nmB = newmB * SC;                    \
        float rsA = 0.f, rsB = 0.f;                                        \
        _Pragma("unroll")                                                  \
        for (int sn_ = 0; sn_ < 4; ++sn_)                                  \
            _Pragma("unroll")                                              \
            for (int r_ = 0; r_ < 4; ++r_) {                               \
                float pa_ = exp2f(__builtin_fmaf(svA[sn_][r_], SC, -nmA)); \
                float pb_ = exp2f(__builtin_fmaf(svB[sn_][r_], SC, -nmB)); \
                svA[sn_][r_] = pa_; rsA += pa_;                            \
                svB[sn_][r_] = pb_; rsB += pb_;                            \
            }                                                              \
        rsA += __shfl_xor(rsA, 16); rsA += __shfl_xor(rsA, 32);            \
        rsB += __shfl_xor(rsB, 16); rsB += __shfl_xor(rsB, 32);            \
        lA = lA * alA + rsA;  lB = lB * alB + rsB;                         \
        _Pragma("unroll")                                                  \
        for (int hs_ = 0; hs_ < 4; ++hs_)                                  \
            _Pragma("unroll")                                              \
            for (int r_ = 0; r_ < 4; ++r_) {                               \
                oA[hs_][r_] *= alA;                                        \
                oB[hs_][r_] *= alB;                                        \
            }                                                              \
        bf16x8 pA0, pA1, pB0, pB1;                                         \
        _Pragma("unroll")                                                  \
        for (int r_ = 0; r_ < 4; ++r_) {                                   \
            pA0[r_]     = (__bf16)svA[0][r_];                              \
            pA0[4 + r_] = (__bf16)svA[1][r_];                              \
            pA1[r_]     = (__bf16)svA[2][r_];                              \
            pA1[4 + r_] = (__bf16)svA[3][r_];                              \
            pB0[r_]     = (__bf16)svB[0][r_];                              \
            pB0[4 + r_] = (__bf16)svB[1][r_];                              \
            pB1[r_]     = (__bf16)svB[2][r_];                              \
            pB1[4 + r_] = (__bf16)svB[3][r_];                              \
        }                                                                  \
        _Pragma("unroll")                                                  \
        for (int hs_ = 0; hs_ < 4; ++hs_) {                                \
            oA[hs_] = __builtin_amdgcn_mfma_f32_16x16x32_bf16(vA[hs_*2],   pA0, oA[hs_], 0, 0, 0); \
            oA[hs_] = __builtin_amdgcn_mfma_f32_16x16x32_bf16(vA[hs_*2+1], pA1, oA[hs_], 0, 0, 0); \
            oB[hs_] = __builtin_amdgcn_mfma_f32_16x16x32_bf16(vA[hs_*2],   pB0, oB[hs_], 0, 0, 0); \
            oB[hs_] = __builtin_amdgcn_mfma_f32_16x16x32_bf16(vA[hs_*2+1], pB1, oB[hs_], 0, 0, 0); \
        }                                                                  \
    }

    auto runPhase = [&](const int f) {
        const int ntiles = (f >> 1) + 1;          // same for both halves
        const int qrowA  = f * 32 + m16;
        const int qrowB  = qrowA + 16;

        bf16x8 qA0 = *(const bf16x8*)(Qb + (size_t)qrowA * 64 + quad * 8);
        bf16x8 qA1 = *(const bf16x8*)(Qb + (size_t)qrowA * 64 + 32 + quad * 8);
        bf16x8 qB0 = *(const bf16x8*)(Qb + (size_t)qrowB * 64 + quad * 8);
        bf16x8 qB1 = *(const bf16x8*)(Qb + (size_t)qrowB * 64 + 32 + quad * 8);

        f32x4 oA[4], oB[4];
        #pragma unroll
        for (int hs = 0; hs < 4; ++hs) {
            oA[hs] = {0.f, 0.f, 0.f, 0.f};
            oB[hs] = {0.f, 0.f, 0.f, 0.f};
        }
        float mA = -3e38f, lA = 0.f, mB = -3e38f, lB = 0.f;

        bf16x8 kA[8], kB[8];
        int jt = wave;                     // 8-way split-K by tile parity
        if (jt < ntiles) {
            LOADK(kA, jt);
            while (true) {
                STEP(kA, kB);
                jt += 8; if (jt >= ntiles) break;
                STEP(kB, kA);
                jt += 8; if (jt >= ntiles) break;
            }
        }

        // 8-way split-K merge: everyone publishes, waves 0/1 combine A/B
        #pragma unroll
        for (int hs = 0; hs < 4; ++hs)
            #pragma unroll
            for (int r = 0; r < 4; ++r) {
                Mrg[wave][lane][hs * 4 + r]      = oA[hs][r];
                Mrg[wave][lane][18 + hs * 4 + r] = oB[hs][r];
            }
        Mrg[wave][lane][16] = mA; Mrg[wave][lane][17] = lA;
        Mrg[wave][lane][34] = mB; Mrg[wave][lane][35] = lB;
        __syncthreads();
        if (wave < 2) {
            const int off  = wave * 18;
            const int qrow = f * 32 + wave * 16 + m16;
            float mw[8], lw[8];
            #pragma unroll
            for (int w = 0; w < 8; ++w) {
                mw[w] = Mrg[w][lane][off + 16];
                lw[w] = Mrg[w][lane][off + 17];
            }
            float M = mw[0];
            #pragma unroll
            for (int w = 1; w < 8; ++w) M = fmaxf(M, mw[w]);
            float aw[8], den = 0.f;
            #pragma unroll
            for (int w = 0; w < 8; ++w) {
                aw[w] = exp2f((mw[w] - M) * SC);
                den += lw[w] * aw[w];
            }
            const float inv = 1.f / den;
            float* Ob = Obase + (size_t)qrow * 64;
            #pragma unroll
            for (int hs = 0; hs < 4; ++hs) {
                f32x4 v;
                #pragma unroll
                for (int r = 0; r < 4; ++r) {
                    float acc = 0.f;
                    #pragma unroll
                    for (int w = 0; w < 8; ++w)
                        acc += Mrg[w][lane][off + hs * 4 + r] * aw[w];
                    v[r] = acc * inv;
                }
                *(f32x4*)(Ob + hs * 16 + quad * 4) = v;
            }
        }
        __syncthreads();   // Mrg reusable for next phase
    };

    runPhase(s);           // (s>>1)+1 tiles
    runPhase(63 - s);      // 32-(s>>1) tiles  -> 33-34 uniform per block
#undef STEP
#undef LOADV
#undef LOADK
}

// ---------------------------------------------------------------------------
extern "C" void kernel_launch(void* const* d_in, const int* in_sizes, int n_in,
                              void* d_out, int out_size, void* d_ws, size_t ws_size,
                              hipStream_t stream)
{
    const float* x  = (const float*)d_in[0];
    const float* Wq = (const float*)d_in[1];
    const float* bq = (const float*)d_in[2];
    const float* Wk = (const float*)d_in[3];
    const float* bk = (const float*)d_in[4];
    const float* Wv = (const float*)d_in[5];
    const float* bv = (const float*)d_in[6];
    float* out = (float*)d_out;

    __bf16* Wp = (__bf16*)d_ws;              // 384*512 bf16         = 0.4 MB
    __bf16* Q  = Wp + 384 * 512;             // 8*2048*64 bf16       = 2 MB
    __bf16* Kp = Q  + (size_t)B_ * T_ * HS_; // frag-packed          = 2 MB
    __bf16* Vp = Kp + (size_t)B_ * T_ * HS_; // frag-packed          = 2 MB

    pack_w<<<96, 256, 0, stream>>>(Wq, Wk, Wv, Wp);
    qkv_fused<<<512, 256, 0, stream>>>(x, Wp, bq, bk, bv, Q, Kp, Vp);
    attn_fused<<<dim3(32, 8), 512, 0, stream>>>(Q, Kp, Vp, out);
}